// Round 6
// baseline (219.727 us; speedup 1.0000x reference)
//
#include <hip/hip_runtime.h>
#include <math.h>

// Problem constants: B=4, T=1024, D_MODEL=1024, H=16, DK=64, R=65 (2*32+1)
//
// Pipeline (4 launches):
//   prep                  : fused cast_qv + transpose_cast_w + transpose_cast_wo
//   mfma_gemm<0,128,false>: fp16 outputs q16a (=qW/8), k16, vt16 (V transposed)
//   attn_kernel v8        : 32x32x16-MFMA flash attention, 64-row q-tiles,
//                           4 waves = 2 col-groups x 2 KEY PARITIES (v5's
//                           proven s-split on v4's proven 64-row geometry).
//                           Per-parity single-buffered K/V staging, v5's
//                           2-barrier schedule. Band in LDS (no global spill).
//                           52.1 KB LDS, grid 1024 blocks -> 3 blocks/CU
//                           (12 waves/CU vs v3's 8). (256,3): ~156 regs, no
//                           spill (v5's spill was the (512,4) 128-reg cap).
//   mfma_gemm<1,64,true>  : out fp32 = heads16 @ W_O^T, 128x64 tiles, dbuf
//
// MFMA orientation convention (verified r3-r7 + m74/m101 C/D map):
//   mfma(A, B, C): A rows on lane&31, B cols on lane&31,
//   D: col = lane&31, row = (reg&3) + 8*(reg>>2) + 4*(lane>>5).
//   S^T : mfma(kf, qf) -> row=s, col=t
//   PV  : mfma(vf, pf) -> row=d, col=t   (pf MUST be the B operand)
//   band: mfma(ef, pf) -> row=d, col=t
//
// LDS map (attn v8):
//   kv[16384] h : Kp0[0..4095] Kp1[4096..8191] Vp0[8192..12287] Vp1[12288..]
//   qEl[4680] h : [65][72] qE bias table; prologue scratch embQ rows 64..95
//   band[4608] h: [64][72] raw band scores; prologue scratch embQ rows 0..63
//   epilogue    : Obuf fp32[64][64] overlays kv halves [0..8191];
//                 eSt [64][64] overlays kv halves [8192..12287]

typedef _Float16 f16;
typedef f16 half8 __attribute__((ext_vector_type(8)));
typedef f16 half4v __attribute__((ext_vector_type(4)));
typedef float f32x4 __attribute__((ext_vector_type(4)));
typedef float f32x16 __attribute__((ext_vector_type(16)));

// ---------------------------------------------------------------------------
// prep: bx<8192 -> cast q,v to fp16; 8192..8959 -> W_{Q,K,V} transpose+cast;
// 8960..9215 -> W_O transpose+cast.
// ---------------------------------------------------------------------------
__global__ __launch_bounds__(256) void prep(
    const float* __restrict__ q, const float* __restrict__ v,
    const float* __restrict__ W0, const float* __restrict__ W1,
    const float* __restrict__ W2, const float* __restrict__ WO,
    f16* __restrict__ q16, f16* __restrict__ Wt16, f16* __restrict__ WOt16) {
    __shared__ float tile[64][65];
    const int bx = blockIdx.x;
    const int t = threadIdx.x;
    if (bx < 8192) {
        int i = (bx * 256 + t) * 4;
        const float* s = (i < 4194304) ? (q + i) : (v + (i - 4194304));
        float4 x = *(const float4*)s;
        half4v h = {(f16)x.x, (f16)x.y, (f16)x.z, (f16)x.w};
        *(half4v*)&q16[i] = h;
        return;
    }
    const int c = t & 63, r4 = t >> 6;
    const int n = t >> 2, kc = (t & 3) * 16;
    if (bx < 8960) {
        const int idx = bx - 8192;
        const int z = idx >> 4, k0 = (idx & 15) * 64;
        const float* src = ((z < 16) ? W0 : (z < 32) ? W1 : W2) + (size_t)(z & 15) * 65536;
        f16* out = Wt16 + (size_t)z * 65536;
#pragma unroll
        for (int p = 0; p < 16; ++p)
            tile[r4 + p * 4][c] = src[(size_t)(k0 + r4 + p * 4) * 64 + c];
        __syncthreads();
        f16 buf[16];
#pragma unroll
        for (int i = 0; i < 16; ++i) buf[i] = (f16)tile[kc + i][n];
        *(half8*)&out[(size_t)n * 1024 + k0 + kc] = *(half8*)&buf[0];
        *(half8*)&out[(size_t)n * 1024 + k0 + kc + 8] = *(half8*)&buf[8];
        return;
    }
    {
        const int idx = bx - 8960;
        const int k0 = (idx & 15) * 64, n0 = (idx >> 4) * 64;
#pragma unroll
        for (int p = 0; p < 16; ++p)
            tile[r4 + p * 4][c] = WO[(size_t)(k0 + r4 + p * 4) * 1024 + n0 + c];
        __syncthreads();
        f16 buf[16];
#pragma unroll
        for (int i = 0; i < 16; ++i) buf[i] = (f16)tile[kc + i][n];
        *(half8*)&WOt16[(size_t)(n0 + n) * 1024 + k0 + kc] = *(half8*)&buf[0];
        *(half8*)&WOt16[(size_t)(n0 + n) * 1024 + k0 + kc + 8] = *(half8*)&buf[8];
    }
}

// ---------------------------------------------------------------------------
// fp16 MFMA GEMM, 128xNT tile (NT = 128 or 64), optional single-barrier
// double-buffered staging. MODE 0: write q16a (acc*0.125), k16, vt16
// (transposed). MODE 1: write fp32 C.
// ---------------------------------------------------------------------------
template <int MODE, int NT, bool DBUF>
__global__ __launch_bounds__(256) void mfma_gemm(
    const f16* __restrict__ Aq, const f16* __restrict__ Av,
    const f16* __restrict__ Bt, float* __restrict__ C,
    f16* __restrict__ oQ, f16* __restrict__ oK, f16* __restrict__ oVt) {
    constexpr int K = 1024;
    constexpr int NI = NT / 32;                 // n-frags per wave
    constexpr int LDSZ = (128 + NT) * 64;       // halves per buffer
    const int n0 = blockIdx.x * NT;
    const int m0 = blockIdx.y * 128;
    const f16* Abase = (MODE == 0) ? ((n0 < 1024) ? Aq : Av) : Aq;

    __shared__ f16 lds[LDSZ * (DBUF ? 2 : 1)];

    const int tid = threadIdx.x;
    const int l = tid & 63, wv = tid >> 6;
    const int rseg = l >> 3;
    const int g = (l & 7) ^ rseg;
    const bool isA = (wv < 2);
    const int rowBase = isA ? (wv & 1) * 64 : (wv & 1) * (NT / 2);
    const int nLoads = isA ? 8 : (NT / 16);
    const f16* gSrc = isA ? (Abase + (size_t)m0 * K) : (Bt + (size_t)n0 * K);
    const f16* gLane = gSrc + (size_t)(rowBase + rseg) * K + g * 8;
    const int ldsRow0 = (isA ? 0 : 128) + rowBase;

    const int fr = l & 15, fq = l >> 4, sw = fr & 7;
    const int mi2 = wv & 1, ni2 = wv >> 1;
    int aOff[NI], bOff[4];
#pragma unroll
    for (int i = 0; i < 4; ++i) bOff[i] = (mi2 * 64 + i * 16 + fr) * 128;
#pragma unroll
    for (int i = 0; i < NI; ++i)
        aOff[i] = (128 + ni2 * (NT / 2) + i * 16 + fr) * 128;

    f32x4 acc[4][NI];
#pragma unroll
    for (int i = 0; i < 4; ++i)
#pragma unroll
        for (int j = 0; j < NI; ++j) acc[i][j] = {0.f, 0.f, 0.f, 0.f};

    auto issue = [&](int k0, int buf) {
        f16* dst = lds + (buf ? LDSZ : 0);
#pragma unroll 8
        for (int i = 0; i < nLoads; ++i) {
            const f16* src = gLane + (size_t)i * 8 * K + k0;
            __builtin_amdgcn_global_load_lds(
                (const __attribute__((address_space(1))) unsigned int*)src,
                (__attribute__((address_space(3))) unsigned int*)
                    &dst[(ldsRow0 + i * 8) * 64], 16, 0, 0);
        }
    };

    if (DBUF) issue(0, 0);
    int it = 0;
    for (int k0 = 0; k0 < K; k0 += 64, ++it) {
        if (!DBUF) issue(k0, 0);
        __syncthreads();
        if (DBUF && k0 + 64 < K) issue(k0 + 64, (it + 1) & 1);
        const char* lp = (const char*)lds + (DBUF ? (it & 1) * (LDSZ * 2) : 0);
#pragma unroll
        for (int kk = 0; kk < 2; ++kk) {
            const int glq = kk * 4 + fq;
            const int sgl = (glq ^ sw) * 16;
            half8 aF[NI], bF[4];
#pragma unroll
            for (int i = 0; i < NI; ++i)
                aF[i] = *(const half8*)(lp + aOff[i] + sgl);
#pragma unroll
            for (int i = 0; i < 4; ++i)
                bF[i] = *(const half8*)(lp + bOff[i] + sgl);
#pragma unroll
            for (int mi = 0; mi < 4; ++mi)
#pragma unroll
                for (int ni = 0; ni < NI; ++ni)
                    acc[mi][ni] = __builtin_amdgcn_mfma_f32_16x16x32_f16(
                        aF[ni], bF[mi], acc[mi][ni], 0, 0, 0);
        }
        if (!DBUF) __syncthreads();
    }
#pragma unroll
    for (int mi = 0; mi < 4; ++mi) {
        const int m = m0 + mi2 * 64 + mi * 16 + fr;
#pragma unroll
        for (int ni = 0; ni < NI; ++ni) {
            const int n = n0 + ni2 * (NT / 2) + ni * 16 + 4 * fq;
            if (MODE == 1) {
                *(f32x4*)(C + (size_t)m * 1024 + n) = acc[mi][ni];
            } else {
                const int w = n >> 10, h = (n >> 6) & 15, d = n & 63;
                const int b = m >> 10, t = m & 1023;
                const size_t bh = (size_t)(b * 16 + h);
                f32x4 a = acc[mi][ni];
                if (w == 0) {
                    half4v hv = {(f16)(a[0] * 0.125f), (f16)(a[1] * 0.125f),
                                 (f16)(a[2] * 0.125f), (f16)(a[3] * 0.125f)};
                    *(half4v*)&oQ[bh * 65536 + (size_t)t * 64 + d] = hv;
                } else if (w == 1) {
                    half4v hv = {(f16)a[0], (f16)a[1], (f16)a[2], (f16)a[3]};
                    *(half4v*)&oK[bh * 65536 + (size_t)t * 64 + d] = hv;
                } else {
#pragma unroll
                    for (int r = 0; r < 4; ++r)
                        oVt[bh * 65536 + (size_t)(d + r) * 1024 + t] = (f16)a[r];
                }
            }
        }
    }
}

// ---------------------------------------------------------------------------
// MFMA flash attention v8: 32x32x16 MFMAs, block = (bh, 64-row q-tile),
// 4 waves = 2 col-groups (tcg = wv&1, 32 t each) x 2 key parities
// (par = wv>>1). Per iteration (8 total) each parity wave-pair stages its own
// 64-key K/V tile (single buffer per parity, v5's proven 2-barrier schedule)
// and computes it. NO-max softmax; P in regs via half-wave shfl. Parity
// partials (rs, rsL, O) combined through LDS (Obuf/eSt overlay dead kv).
// ---------------------------------------------------------------------------
__global__ __launch_bounds__(256, 3) void attn_kernel(
    const f16* __restrict__ q16a, const f16* __restrict__ k16,
    const f16* __restrict__ vt16, const float* __restrict__ embQ,
    const float* __restrict__ embS, f16* __restrict__ heads16) {
    const int bh = blockIdx.x;
    const int t0 = blockIdx.y * 64;
    const f16* qg = q16a + (size_t)bh * 65536;
    const f16* kg = k16 + (size_t)bh * 65536;
    const f16* vg = vt16 + (size_t)bh * 65536;

    __shared__ __align__(16) f16 kv[16384];   // Kp0|Kp1|Vp0|Vp1 (swizzled)
    __shared__ __align__(16) f16 qEl[4680];   // [65][72]; prologue scratch
    __shared__ __align__(16) f16 band[4608];  // [64][72]; prologue scratch
    __shared__ float redS[128];               // [tl] rs, [64+tl] rsL partials
    __shared__ float e64s[64];

    const int tid = threadIdx.x;
    const int wv = tid >> 6, lane = tid & 63;
    const int tl32 = lane & 31, h = lane >> 5;
    const int tcg = wv & 1, par = wv >> 1;
    const int tl = tcg * 32 + tl32;      // t-col within block: 0..63
    const int tg = t0 + tl;

    auto stageKV = [&](int it8) {
        const int j0 = it8 * 128 + par * 64;   // this parity's 64-key tile
#pragma unroll
        for (int k = 0; k < 4; ++k) {
            const int rr = tcg * 32 + k * 8;
            const int rt = rr + (lane >> 3);
            const int g = (lane & 7) ^ (rt & 7);
            __builtin_amdgcn_global_load_lds(
                (const __attribute__((address_space(1))) unsigned int*)
                    (kg + (size_t)(j0 + rt) * 64 + g * 8),
                (__attribute__((address_space(3))) unsigned int*)
                    &kv[par * 4096 + rr * 64], 16, 0, 0);
            __builtin_amdgcn_global_load_lds(
                (const __attribute__((address_space(1))) unsigned int*)
                    (vg + (size_t)rt * 1024 + j0 + g * 8),
                (__attribute__((address_space(3))) unsigned int*)
                    &kv[8192 + par * 4096 + rr * 64], 16, 0, 0);
        }
    };

    // Q B-frags first (oldest vmcnt slots), then preload tile 0 (both par).
    half8 qf[4];
#pragma unroll
    for (int ks = 0; ks < 4; ++ks)
        qf[ks] = *(const half8*)&qg[(size_t)tg * 64 + (2 * ks + h) * 8];
    stageKV(0);

    // ---- stage embQ swizzled: rows 0..63 -> band scratch, 64..95 -> qEl ----
    // (rows 65..95 zero-padded for the 3-row-tile qE MFMA)
    for (int idx = tid; idx < 768; idx += 256) {
        const int row = idx >> 3, p = idx & 7, g = p ^ (row & 7);
        half8 hv;
        if (row < 65) {
            const float* s = embQ + row * 64 + g * 8;
#pragma unroll
            for (int j = 0; j < 8; ++j) hv[j] = (f16)s[j];
        } else {
#pragma unroll
            for (int j = 0; j < 8; ++j) hv[j] = (f16)0.f;
        }
        f16* base = (row < 64) ? (band + row * 64) : (qEl + (row - 64) * 64);
        *(half8*)&base[p * 8] = hv;
    }
    __syncthreads();
    // ---- fused qE: qEl[r][tl] = embQ[r] . Q[tg] ----
    // par==0: row-tiles 0,1 (rows 0..63 from band scratch);
    // par==1: row-tile 2 (rows 64..95 from qEl scratch; only row 64 kept).
    {
        f32x16 qacc[2];
#pragma unroll
        for (int mt = 0; mt < 2; ++mt)
#pragma unroll
            for (int r = 0; r < 16; ++r) qacc[mt][r] = 0.f;
        if (par == 0) {
#pragma unroll
            for (int ks = 0; ks < 4; ++ks)
#pragma unroll
                for (int mt = 0; mt < 2; ++mt) {
                    const int row = tl32 + 32 * mt;
                    const int p = (2 * ks + h) ^ (row & 7);
                    half8 ef = *(const half8*)&band[row * 64 + p * 8];
                    qacc[mt] = __builtin_amdgcn_mfma_f32_32x32x16_f16(
                        ef, qf[ks], qacc[mt], 0, 0, 0);
                }
        } else {
#pragma unroll
            for (int ks = 0; ks < 4; ++ks) {
                const int row = tl32 + 64;
                const int p = (2 * ks + h) ^ (row & 7);
                half8 ef = *(const half8*)&qEl[(row - 64) * 64 + p * 8];
                qacc[0] = __builtin_amdgcn_mfma_f32_32x32x16_f16(
                    ef, qf[ks], qacc[0], 0, 0, 0);
            }
        }
        __syncthreads();   // embQ scratch consumed; qEl/band reusable
        if (par == 0) {
#pragma unroll
            for (int mt = 0; mt < 2; ++mt)
#pragma unroll
                for (int r = 0; r < 16; ++r) {
                    const int rr = (r & 3) + 8 * (r >> 2) + 4 * h + 32 * mt;
                    qEl[rr * 72 + tl] = (f16)qacc[mt][r];
                }
        } else {
            // rr = (r&3)+8*(r>>2)+4*h+64 < 65  <=>  r==0 && h==0
            if (h == 0) qEl[64 * 72 + tl] = (f16)qacc[0][0];
        }
    }
    // init band to -1e4 (exp -> 0); disjoint from qEl writes above
    for (int idx = tid; idx < 576; idx += 256) {
        half8 hv;
#pragma unroll
        for (int j = 0; j < 8; ++j) hv[j] = (f16)(-1.0e4f);
        *(half8*)&band[idx * 8] = hv;
    }
    if (tid < 64) e64s[tid] = embS[64 * 64 + tid];
    __syncthreads();   // prologue done; stage(0) drained at barriers above
    const float qE0 = (float)qEl[tl];
    const float qE64 = (float)qEl[64 * 72 + tl];

    float rs = 0.f, rsL = 0.f;
    f32x16 oacc[2];
#pragma unroll
    for (int dt = 0; dt < 2; ++dt)
#pragma unroll
        for (int r = 0; r < 16; ++r) oacc[dt][r] = 0.f;

    // ---- main loop: 8 iters, each parity computes its own 64-key tile ----
    for (int it8 = 0; it8 < 8; ++it8) {
        const int j0 = it8 * 128 + par * 64;
        const f16* Ktc = kv + par * 4096;
        const f16* Vtc = kv + 8192 + par * 4096;
        // S^T = K @ Q^T : D[m=s][n=t], col = t(lane&31)
        f32x16 sacc[2];
#pragma unroll
        for (int mt = 0; mt < 2; ++mt)
#pragma unroll
            for (int r = 0; r < 16; ++r) sacc[mt][r] = 0.f;
#pragma unroll
        for (int ks = 0; ks < 4; ++ks)
#pragma unroll
            for (int mt = 0; mt < 2; ++mt) {
                const int row = tl32 + 32 * mt;
                const int p = (2 * ks + h) ^ (row & 7);
                half8 kf = *(const half8*)&Ktc[row * 64 + p * 8];
                sacc[mt] = __builtin_amdgcn_mfma_f32_32x32x16_f16(
                    kf, qf[ks], sacc[mt], 0, 0, 0);
            }
        // bias + exp (+band capture on diagonal tiles)
        const int dj = j0 - t0;
        if (dj <= -128 || dj >= 128) {
            const float bias = (dj < 0) ? qE0 : qE64;
            float ts = 0.f;
#pragma unroll
            for (int mt = 0; mt < 2; ++mt)
#pragma unroll
                for (int r = 0; r < 16; ++r) {
                    float pe = __expf(sacc[mt][r] + bias);
                    sacc[mt][r] = pe; ts += pe;
                }
            rs += ts;
            if (dj < 0) rsL += ts;
        } else {
#pragma unroll
            for (int mt = 0; mt < 2; ++mt)
#pragma unroll
                for (int r = 0; r < 16; ++r) {
                    const int sg = j0 + 32 * mt + (r & 3) + 8 * (r >> 2) + 4 * h;
                    const int ds = sg - tg;
                    const int dc = ds < -32 ? -32 : (ds > 32 ? 32 : ds);
                    float v = sacc[mt][r] + (float)qEl[(dc + 32) * 72 + tl];
                    if (ds >= -31 && ds <= 31) band[tl * 72 + ds + 31] = (f16)v;
                    float pe = __expf(v);
                    sacc[mt][r] = pe; rs += pe;
                    if (ds <= -32) rsL += pe;
                }
        }
        // PV: O[d][t] += V^T @ P^T ; P B-frag via half-wave shfl exchange
#pragma unroll
        for (int ks = 0; ks < 4; ++ks) {
            const int mtile = ks >> 1, rb = (ks & 1) * 8;
            float ex[4];
#pragma unroll
            for (int c = 0; c < 4; ++c) {
                float send = (h == 0) ? sacc[mtile][rb + 4 + c]
                                      : sacc[mtile][rb + c];
                ex[c] = __shfl_xor(send, 32);
            }
            half8 pf;
#pragma unroll
            for (int j = 0; j < 4; ++j)
                pf[j] = (f16)((h == 0) ? sacc[mtile][rb + j] : ex[j]);
#pragma unroll
            for (int j = 0; j < 4; ++j)
                pf[4 + j] = (f16)((h == 0) ? ex[j] : sacc[mtile][rb + 4 + j]);
#pragma unroll
            for (int dt = 0; dt < 2; ++dt) {
                const int row = tl32 + 32 * dt;
                const int p = (2 * ks + h) ^ (row & 7);
                half8 vf = *(const half8*)&Vtc[row * 64 + p * 8];
                // A = vf (rows = d), B = pf (cols = t)  ->  D[row=d][col=t]
                oacc[dt] = __builtin_amdgcn_mfma_f32_32x32x16_f16(
                    vf, pf, oacc[dt], 0, 0, 0);
            }
        }
        __syncthreads();                       // this tile's LDS reads done
        if (it8 < 7) {
            stageKV(it8 + 1);                  // refill own parity buffer
            __syncthreads();                   // stage complete (vmcnt drained)
        }
    }
    // ---- epilogue: combine parity partials, band/eS terms, store ----------
    rs += __shfl_xor(rs, 32);
    rsL += __shfl_xor(rsL, 32);
    float* Obuf = (float*)kv;        // kv halves [0..8191]  (Kp0|Kp1, dead)
    f16* eSt = kv + 8192;            // kv halves [8192..12287] (Vp0, dead)
    if (par == 1) {
        if (h == 0) { redS[tl] = rs; redS[64 + tl] = rsL; }
#pragma unroll
        for (int dt = 0; dt < 2; ++dt)
#pragma unroll
            for (int r = 0; r < 16; ++r) {
                const int d = (r & 3) + 8 * (r >> 2) + 4 * h + 32 * dt;
                Obuf[d * 64 + tl] = oacc[dt][r];
            }
    }
    // ALL: stage eSt[d][k] = embS[(k==63?0:k+1)][d] swizzled
    for (int idx = tid; idx < 512; idx += 256) {
        const int d = idx >> 3, p = idx & 7, g = p ^ (d & 7);
        half8 hv;
#pragma unroll
        for (int j = 0; j < 8; ++j) {
            const int k = g * 8 + j;
            hv[j] = (f16)embS[((k == 63) ? 0 : (k + 1)) * 64 + d];
        }
        *(half8*)&eSt[d * 64 + p * 8] = hv;
    }
    __syncthreads();   // partials + eSt published
    float sumR = 0.f, inv = 0.f;
    if (par == 0) {
        rs += redS[tl];
        rsL += redS[64 + tl];
#pragma unroll
        for (int dt = 0; dt < 2; ++dt)
#pragma unroll
            for (int r = 0; r < 16; ++r) {
                const int d = (r & 3) + 8 * (r >> 2) + 4 * h + 32 * dt;
                oacc[dt][r] += Obuf[d * 64 + tl];
            }
        // exp band in place; slot 63 = rsL (pairs embS[0] = left bucket)
        float sumBand = 0.f;
#pragma unroll
        for (int c = 0; c < 4; ++c) {
            const int kb = 32 * h + 8 * c;
            half8 bv = *(const half8*)&band[tl * 72 + kb];
            half8 ev;
#pragma unroll
            for (int j = 0; j < 8; ++j) {
                const int k = kb + j;
                float v;
                if (k == 63) v = rsL;
                else { v = __expf((float)bv[j]); sumBand += v; }
                ev[j] = (f16)v;
            }
            *(half8*)&band[tl * 72 + kb] = ev;
        }
        sumBand += __shfl_xor(sumBand, 32);
        sumR = rs - rsL - sumBand;
        inv = 1.0f / rs;
    }
    __syncthreads();   // band-exp visible (cross half-wave pf reads)
    // O += eSt @ Pband^T   (A = ef rows = d, B = pf cols = t) — par==0 waves
    if (par == 0) {
#pragma unroll
        for (int ks = 0; ks < 4; ++ks) {
            half8 pf = *(const half8*)&band[tl * 72 + 16 * ks + 8 * h];
#pragma unroll
            for (int dt = 0; dt < 2; ++dt) {
                const int row = tl32 + 32 * dt;
                const int p = (2 * ks + h) ^ (row & 7);
                half8 ef = *(const half8*)&eSt[row * 64 + p * 8];
                oacc[dt] = __builtin_amdgcn_mfma_f32_32x32x16_f16(
                    ef, pf, oacc[dt], 0, 0, 0);
            }
        }
    }
    __syncthreads();   // band (Pband) reads done before O-transpose overwrite
    // O (row=d, col=own t) -> band space [tl][d]
    if (par == 0) {
#pragma unroll
        for (int dt = 0; dt < 2; ++dt)
#pragma unroll
            for (int r = 0; r < 16; ++r) {
                const int d = (r & 3) + 8 * (r >> 2) + 4 * h + 32 * dt;
                band[tl * 72 + d] = (f16)((oacc[dt][r] + sumR * e64s[d]) * inv);
            }
    }
    __syncthreads();
    // coalesced global store: 64 rows x 64 halves, 2x half8 per thread
    const int b = bh >> 4, hh = bh & 15;
    const int row = tid >> 2, cb = (tid & 3) * 16;
    f16* dst = heads16 + ((size_t)(b * 1024 + t0 + row) * 1024) + hh * 64 + cb;
    *(half8*)&dst[0] = *(const half8*)&band[row * 72 + cb];
    *(half8*)&dst[8] = *(const half8*)&band[row * 72 + cb + 8];
}

// ---------------------------------------------------------------------------
extern "C" void kernel_launch(void* const* d_in, const int* in_sizes, int n_in,
                              void* d_out, int out_size, void* d_ws, size_t ws_size,
                              hipStream_t stream) {
    const float* query = (const float*)d_in[0];
    const float* value = (const float*)d_in[1];
    const float* WQ   = (const float*)d_in[2];
    const float* WK   = (const float*)d_in[3];
    const float* WV   = (const float*)d_in[4];
    const float* WO   = (const float*)d_in[5];
    const float* embQ = (const float*)d_in[6];
    const float* embS = (const float*)d_in[7];
    float* out = (float*)d_out;

    f16* w0    = (f16*)d_ws;
    f16* q16   = w0;                 // 4,194,304 h (+ v16 contiguous)
    f16* v16   = w0 + 4194304;       // 4,194,304 h
    f16* Wt16  = w0 + 8388608;       // 3,145,728 h
    f16* WOt16 = w0 + 11534336;      // 1,048,576 h
    f16* q16a  = w0 + 12582912;      // 4,194,304 h (qW/8)
    f16* k16   = w0 + 16777216;      // 4,194,304 h
    f16* vt16  = w0 + 20971520;      // 4,194,304 h (V transposed [bh][d][t])
    f16* h16   = w0 + 25165824;      // 4,194,304 h  (end: 58.7 MB)

    prep<<<9216, 256, 0, stream>>>(query, value, WQ, WK, WV, WO,
                                   q16, Wt16, WOt16);
    mfma_gemm<0, 128, false><<<dim3(24, 32), 256, 0, stream>>>(
        q16, v16, Wt16, nullptr, q16a, k16, vt16);
    attn_kernel<<<dim3(64, 16), 256, 0, stream>>>(q16a, k16, vt16, embQ, embS, h16);
    mfma_gemm<1, 64, true><<<dim3(16, 32), 256, 0, stream>>>(
        h16, h16, WOt16, out, nullptr, nullptr, nullptr);
}

// Round 7
// 206.931 us; speedup vs baseline: 1.0618x; 1.0618x over previous
//
#include <hip/hip_runtime.h>
#include <math.h>

// Problem constants: B=4, T=1024, D_MODEL=1024, H=16, DK=64, R=65 (2*32+1)
//
// Pipeline (4 launches):
//   prep                  : fused cast_qv + transpose_cast_w + transpose_cast_wo
//   mfma_gemm<0,128,true> : fp16 outputs q16a (=qW/8), k16, vt16 (V transposed)
//                           NOW double-buffered + XCD-swizzled flat grid.
//   attn_kernel           : v3 verbatim (52.5 us proven): 32x32x16-MFMA flash
//                           attention, 128t/block, fused qE, NO-max softmax,
//                           P in regs (shfl exchange), single-barrier
//                           DOUBLE-BUFFERED K/V staging.
//   mfma_gemm<1,64,true>  : out fp32 = heads16 @ W_O^T, XCD-swizzled flat grid
//
// MFMA orientation convention (verified r3-r7 + m74/m101 C/D map):
//   mfma(A, B, C): A rows on lane&31, B cols on lane&31,
//   D: col = lane&31, row = (reg&3) + 8*(reg>>2) + 4*(lane>>5).
//   S^T : mfma(kf, qf) -> row=s, col=t
//   PV  : mfma(vf, pf) -> row=d, col=t   (pf MUST be the B operand)
//   band: mfma(ef, pf) -> row=d, col=t

typedef _Float16 f16;
typedef f16 half8 __attribute__((ext_vector_type(8)));
typedef f16 half4v __attribute__((ext_vector_type(4)));
typedef float f32x4 __attribute__((ext_vector_type(4)));
typedef float f32x16 __attribute__((ext_vector_type(16)));

// ---------------------------------------------------------------------------
// prep: bx<8192 -> cast q,v to fp16; 8192..8959 -> W_{Q,K,V} transpose+cast;
// 8960..9215 -> W_O transpose+cast.
// ---------------------------------------------------------------------------
__global__ __launch_bounds__(256) void prep(
    const float* __restrict__ q, const float* __restrict__ v,
    const float* __restrict__ W0, const float* __restrict__ W1,
    const float* __restrict__ W2, const float* __restrict__ WO,
    f16* __restrict__ q16, f16* __restrict__ Wt16, f16* __restrict__ WOt16) {
    __shared__ float tile[64][65];
    const int bx = blockIdx.x;
    const int t = threadIdx.x;
    if (bx < 8192) {
        int i = (bx * 256 + t) * 4;
        const float* s = (i < 4194304) ? (q + i) : (v + (i - 4194304));
        float4 x = *(const float4*)s;
        half4v h = {(f16)x.x, (f16)x.y, (f16)x.z, (f16)x.w};
        *(half4v*)&q16[i] = h;
        return;
    }
    const int c = t & 63, r4 = t >> 6;
    const int n = t >> 2, kc = (t & 3) * 16;
    if (bx < 8960) {
        const int idx = bx - 8192;
        const int z = idx >> 4, k0 = (idx & 15) * 64;
        const float* src = ((z < 16) ? W0 : (z < 32) ? W1 : W2) + (size_t)(z & 15) * 65536;
        f16* out = Wt16 + (size_t)z * 65536;
#pragma unroll
        for (int p = 0; p < 16; ++p)
            tile[r4 + p * 4][c] = src[(size_t)(k0 + r4 + p * 4) * 64 + c];
        __syncthreads();
        f16 buf[16];
#pragma unroll
        for (int i = 0; i < 16; ++i) buf[i] = (f16)tile[kc + i][n];
        *(half8*)&out[(size_t)n * 1024 + k0 + kc] = *(half8*)&buf[0];
        *(half8*)&out[(size_t)n * 1024 + k0 + kc + 8] = *(half8*)&buf[8];
        return;
    }
    {
        const int idx = bx - 8960;
        const int k0 = (idx & 15) * 64, n0 = (idx >> 4) * 64;
#pragma unroll
        for (int p = 0; p < 16; ++p)
            tile[r4 + p * 4][c] = WO[(size_t)(k0 + r4 + p * 4) * 1024 + n0 + c];
        __syncthreads();
        f16 buf[16];
#pragma unroll
        for (int i = 0; i < 16; ++i) buf[i] = (f16)tile[kc + i][n];
        *(half8*)&WOt16[(size_t)(n0 + n) * 1024 + k0 + kc] = *(half8*)&buf[0];
        *(half8*)&WOt16[(size_t)(n0 + n) * 1024 + k0 + kc + 8] = *(half8*)&buf[8];
    }
}

// ---------------------------------------------------------------------------
// fp16 MFMA GEMM, 128xNT tile (NT = 128 or 64), single-barrier double-buffered
// staging, FLAT grid with bijective XCD swizzle (m204; nwg%8==0 for both
// instantiations). MODE 0: write q16a (acc*0.125), k16, vt16 (transposed),
// NX=24 n-tiles. MODE 1: write fp32 C, NX=16 n-tiles.
// ---------------------------------------------------------------------------
template <int MODE, int NT, bool DBUF>
__global__ __launch_bounds__(256) void mfma_gemm(
    const f16* __restrict__ Aq, const f16* __restrict__ Av,
    const f16* __restrict__ Bt, float* __restrict__ C,
    f16* __restrict__ oQ, f16* __restrict__ oK, f16* __restrict__ oVt) {
    constexpr int K = 1024;
    constexpr int NI = NT / 32;                 // n-frags per wave
    constexpr int LDSZ = (128 + NT) * 64;       // halves per buffer
    constexpr int NX = (MODE == 0) ? 24 : 16;   // n-tiles in grid
    // XCD-aware bijective swizzle: consecutive swz ids (same XCD L2) walk
    // n-tiles fastest -> A-panel reuse within an XCD chunk.
    const int f = blockIdx.x;
    const int cpx = gridDim.x >> 3;             // nwg/8 (both grids %8==0)
    const int swz = (f & 7) * cpx + (f >> 3);
    const int n0 = (swz % NX) * NT;
    const int m0 = (swz / NX) * 128;
    const f16* Abase = (MODE == 0) ? ((n0 < 1024) ? Aq : Av) : Aq;

    __shared__ f16 lds[LDSZ * (DBUF ? 2 : 1)];

    const int tid = threadIdx.x;
    const int l = tid & 63, wv = tid >> 6;
    const int rseg = l >> 3;
    const int g = (l & 7) ^ rseg;
    const bool isA = (wv < 2);
    const int rowBase = isA ? (wv & 1) * 64 : (wv & 1) * (NT / 2);
    const int nLoads = isA ? 8 : (NT / 16);
    const f16* gSrc = isA ? (Abase + (size_t)m0 * K) : (Bt + (size_t)n0 * K);
    const f16* gLane = gSrc + (size_t)(rowBase + rseg) * K + g * 8;
    const int ldsRow0 = (isA ? 0 : 128) + rowBase;

    const int fr = l & 15, fq = l >> 4, sw = fr & 7;
    const int mi2 = wv & 1, ni2 = wv >> 1;
    int aOff[NI], bOff[4];
#pragma unroll
    for (int i = 0; i < 4; ++i) bOff[i] = (mi2 * 64 + i * 16 + fr) * 128;
#pragma unroll
    for (int i = 0; i < NI; ++i)
        aOff[i] = (128 + ni2 * (NT / 2) + i * 16 + fr) * 128;

    f32x4 acc[4][NI];
#pragma unroll
    for (int i = 0; i < 4; ++i)
#pragma unroll
        for (int j = 0; j < NI; ++j) acc[i][j] = {0.f, 0.f, 0.f, 0.f};

    auto issue = [&](int k0, int buf) {
        f16* dst = lds + (buf ? LDSZ : 0);
#pragma unroll 8
        for (int i = 0; i < nLoads; ++i) {
            const f16* src = gLane + (size_t)i * 8 * K + k0;
            __builtin_amdgcn_global_load_lds(
                (const __attribute__((address_space(1))) unsigned int*)src,
                (__attribute__((address_space(3))) unsigned int*)
                    &dst[(ldsRow0 + i * 8) * 64], 16, 0, 0);
        }
    };

    if (DBUF) issue(0, 0);
    int it = 0;
    for (int k0 = 0; k0 < K; k0 += 64, ++it) {
        if (!DBUF) issue(k0, 0);
        __syncthreads();
        if (DBUF && k0 + 64 < K) issue(k0 + 64, (it + 1) & 1);
        const char* lp = (const char*)lds + (DBUF ? (it & 1) * (LDSZ * 2) : 0);
#pragma unroll
        for (int kk = 0; kk < 2; ++kk) {
            const int glq = kk * 4 + fq;
            const int sgl = (glq ^ sw) * 16;
            half8 aF[NI], bF[4];
#pragma unroll
            for (int i = 0; i < NI; ++i)
                aF[i] = *(const half8*)(lp + aOff[i] + sgl);
#pragma unroll
            for (int i = 0; i < 4; ++i)
                bF[i] = *(const half8*)(lp + bOff[i] + sgl);
#pragma unroll
            for (int mi = 0; mi < 4; ++mi)
#pragma unroll
                for (int ni = 0; ni < NI; ++ni)
                    acc[mi][ni] = __builtin_amdgcn_mfma_f32_16x16x32_f16(
                        aF[ni], bF[mi], acc[mi][ni], 0, 0, 0);
        }
        if (!DBUF) __syncthreads();
    }
#pragma unroll
    for (int mi = 0; mi < 4; ++mi) {
        const int m = m0 + mi2 * 64 + mi * 16 + fr;
#pragma unroll
        for (int ni = 0; ni < NI; ++ni) {
            const int n = n0 + ni2 * (NT / 2) + ni * 16 + 4 * fq;
            if (MODE == 1) {
                *(f32x4*)(C + (size_t)m * 1024 + n) = acc[mi][ni];
            } else {
                const int w = n >> 10, h = (n >> 6) & 15, d = n & 63;
                const int b = m >> 10, t = m & 1023;
                const size_t bh = (size_t)(b * 16 + h);
                f32x4 a = acc[mi][ni];
                if (w == 0) {
                    half4v hv = {(f16)(a[0] * 0.125f), (f16)(a[1] * 0.125f),
                                 (f16)(a[2] * 0.125f), (f16)(a[3] * 0.125f)};
                    *(half4v*)&oQ[bh * 65536 + (size_t)t * 64 + d] = hv;
                } else if (w == 1) {
                    half4v hv = {(f16)a[0], (f16)a[1], (f16)a[2], (f16)a[3]};
                    *(half4v*)&oK[bh * 65536 + (size_t)t * 64 + d] = hv;
                } else {
#pragma unroll
                    for (int r = 0; r < 4; ++r)
                        oVt[bh * 65536 + (size_t)(d + r) * 1024 + t] = (f16)a[r];
                }
            }
        }
    }
}

// ---------------------------------------------------------------------------
// MFMA flash attention v3 (proven 52.5 us): 32x32x16 MFMAs, block = (bh,
// 128-row q-tile), 4 waves x 32 t. NO-max softmax. P in regs (shfl_xor(32)
// exchange). K/V staged unpadded+XOR-swizzled via global_load_lds into DOUBLE
// buffers: one barrier per iter; loads for tile j+1 fly during compute of j.
// ---------------------------------------------------------------------------
__global__ __launch_bounds__(256, 2) void attn_kernel(
    const f16* __restrict__ q16a, const f16* __restrict__ k16,
    const f16* __restrict__ vt16, const float* __restrict__ embQ,
    const float* __restrict__ embS, f16* __restrict__ heads16) {
    const int bh = blockIdx.x;
    const int t0 = blockIdx.y * 128;
    const f16* qg = q16a + (size_t)bh * 65536;
    const f16* kg = k16 + (size_t)bh * 65536;
    const f16* vg = vt16 + (size_t)bh * 65536;

    __shared__ f16 Kt[2][4096];     // [s][d] 64x64, swizzled; Kt[0] = eSt at end
    __shared__ f16 Vt[2][4096];     // [d][s] 64x64, swizzled
    __shared__ f16 qEl[66 * 136];   // [r][tl] r=0..64, tl=0..127
    __shared__ f16 band[128 * 72];  // [tl][k] raw scores; also embQ staging
                                    // (prologue) and O transpose (epilogue)
    __shared__ float e64s[64];

    const int tid = threadIdx.x;
    const int wv = tid >> 6, lane = tid & 63;
    const int tl32 = lane & 31, h = lane >> 5;
    const int tl = wv * 32 + tl32;       // 0..127
    const int tg = t0 + tl;

    auto stageKV = [&](int j0, int buf) {
#pragma unroll
        for (int i = 0; i < 2; ++i) {
            const int rt = wv * 16 + i * 8 + (lane >> 3);
            const int g = (lane & 7) ^ (rt & 7);
            __builtin_amdgcn_global_load_lds(
                (const __attribute__((address_space(1))) unsigned int*)
                    (kg + (size_t)(j0 + rt) * 64 + g * 8),
                (__attribute__((address_space(3))) unsigned int*)
                    &Kt[buf][(wv * 16 + i * 8) * 64], 16, 0, 0);
            __builtin_amdgcn_global_load_lds(
                (const __attribute__((address_space(1))) unsigned int*)
                    (vg + (size_t)rt * 1024 + j0 + g * 8),
                (__attribute__((address_space(3))) unsigned int*)
                    &Vt[buf][(wv * 16 + i * 8) * 64], 16, 0, 0);
        }
    };

    // Q B-frags first (oldest vmcnt slots), then preload tile 0 -> buffer 0.
    half8 qf[4];
#pragma unroll
    for (int ks = 0; ks < 4; ++ks)
        qf[ks] = *(const half8*)&qg[(size_t)tg * 64 + (2 * ks + h) * 8];
    stageKV(0, 0);

    // ---- stage embQ swizzled [row][64] into band space (rows 65..95 zero) --
    f16* embQs = band;
    for (int idx = tid; idx < 768; idx += 256) {
        const int row = idx >> 3, p = idx & 7, g = p ^ (row & 7);
        half8 hv;
        if (row < 65) {
            const float* s = embQ + row * 64 + g * 8;
#pragma unroll
            for (int j = 0; j < 8; ++j) hv[j] = (f16)s[j];
        } else {
#pragma unroll
            for (int j = 0; j < 8; ++j) hv[j] = (f16)0.f;
        }
        *(half8*)&embQs[row * 64 + p * 8] = hv;
    }
    __syncthreads();
    // ---- fused qE: qEl[r][tl] = embQ[r] . Q[tg]  (D: row=r, col=t) ----
    {
        f32x16 qacc[3];
#pragma unroll
        for (int mt = 0; mt < 3; ++mt)
#pragma unroll
            for (int r = 0; r < 16; ++r) qacc[mt][r] = 0.f;
#pragma unroll
        for (int ks = 0; ks < 4; ++ks)
#pragma unroll
            for (int mt = 0; mt < 3; ++mt) {
                const int row = tl32 + 32 * mt;
                const int p = (2 * ks + h) ^ (row & 7);
                half8 ef = *(const half8*)&embQs[row * 64 + p * 8];
                qacc[mt] = __builtin_amdgcn_mfma_f32_32x32x16_f16(
                    ef, qf[ks], qacc[mt], 0, 0, 0);
            }
        __syncthreads();   // embQs reads done; band space reusable
#pragma unroll
        for (int mt = 0; mt < 3; ++mt)
#pragma unroll
            for (int r = 0; r < 16; ++r) {
                const int rr = (r & 3) + 8 * (r >> 2) + 4 * h + 32 * mt;
                if (rr < 65) qEl[rr * 136 + tl] = (f16)qacc[mt][r];
            }
    }
    // init band to -1e4 (exp -> 0)
    for (int idx = tid; idx < 1152; idx += 256) {
        half8 hv;
#pragma unroll
        for (int j = 0; j < 8; ++j) hv[j] = (f16)(-1.0e4f);
        *(half8*)&band[idx * 8] = hv;
    }
    if (tid < 64) e64s[tid] = embS[64 * 64 + tid];
    __syncthreads();
    const float qE0 = (float)qEl[tl];
    const float qE64 = (float)qEl[64 * 136 + tl];

    float rs = 0.f, rsL = 0.f;
    f32x16 oacc[2];
#pragma unroll
    for (int dt = 0; dt < 2; ++dt)
#pragma unroll
        for (int r = 0; r < 16; ++r) oacc[dt][r] = 0.f;

    for (int jt = 0; jt < 16; ++jt) {
        const int j0 = jt * 64;
        __syncthreads();   // tile jt staged; prev compute's LDS reads done
        if (jt < 15) stageKV(j0 + 64, (jt + 1) & 1);
        const f16* Ktc = Kt[jt & 1];
        const f16* Vtc = Vt[jt & 1];
        // S^T = K @ Q^T : D[m=s][n=t], col = t(lane&31)
        f32x16 sacc[2];
#pragma unroll
        for (int mt = 0; mt < 2; ++mt)
#pragma unroll
            for (int r = 0; r < 16; ++r) sacc[mt][r] = 0.f;
#pragma unroll
        for (int ks = 0; ks < 4; ++ks)
#pragma unroll
            for (int mt = 0; mt < 2; ++mt) {
                const int row = tl32 + 32 * mt;
                const int p = (2 * ks + h) ^ (row & 7);
                half8 kf = *(const half8*)&Ktc[row * 64 + p * 8];
                sacc[mt] = __builtin_amdgcn_mfma_f32_32x32x16_f16(
                    kf, qf[ks], sacc[mt], 0, 0, 0);
            }
        // bias + exp (+band capture on diagonal tiles)
        const int dj = j0 - t0;
        if (dj <= -128 || dj >= 192) {
            const float bias = (dj < 0) ? qE0 : qE64;
            float ts = 0.f;
#pragma unroll
            for (int mt = 0; mt < 2; ++mt)
#pragma unroll
                for (int r = 0; r < 16; ++r) {
                    float pe = __expf(sacc[mt][r] + bias);
                    sacc[mt][r] = pe; ts += pe;
                }
            rs += ts;
            if (dj < 0) rsL += ts;
        } else {
#pragma unroll
            for (int mt = 0; mt < 2; ++mt)
#pragma unroll
                for (int r = 0; r < 16; ++r) {
                    const int sg = j0 + 32 * mt + (r & 3) + 8 * (r >> 2) + 4 * h;
                    const int ds = sg - tg;
                    const int dc = ds < -32 ? -32 : (ds > 32 ? 32 : ds);
                    float v = sacc[mt][r] + (float)qEl[(dc + 32) * 136 + tl];
                    if (ds >= -31 && ds <= 31) band[tl * 72 + ds + 31] = (f16)v;
                    float pe = __expf(v);
                    sacc[mt][r] = pe; rs += pe;
                    if (ds <= -32) rsL += pe;
                }
        }
        // PV: O[d][t] += V^T @ P^T ; P B-frag via half-wave shfl exchange
#pragma unroll
        for (int ks = 0; ks < 4; ++ks) {
            const int mtile = ks >> 1, rb = (ks & 1) * 8;
            float ex[4];
#pragma unroll
            for (int c = 0; c < 4; ++c) {
                float send = (h == 0) ? sacc[mtile][rb + 4 + c]
                                      : sacc[mtile][rb + c];
                ex[c] = __shfl_xor(send, 32);
            }
            half8 pf;
#pragma unroll
            for (int j = 0; j < 4; ++j)
                pf[j] = (f16)((h == 0) ? sacc[mtile][rb + j] : ex[j]);
#pragma unroll
            for (int j = 0; j < 4; ++j)
                pf[4 + j] = (f16)((h == 0) ? ex[j] : sacc[mtile][rb + 4 + j]);
#pragma unroll
            for (int dt = 0; dt < 2; ++dt) {
                const int row = tl32 + 32 * dt;
                const int p = (2 * ks + h) ^ (row & 7);
                half8 vf = *(const half8*)&Vtc[row * 64 + p * 8];
                // A = vf (rows = d), B = pf (cols = t)  ->  D[row=d][col=t]
                oacc[dt] = __builtin_amdgcn_mfma_f32_32x32x16_f16(
                    vf, pf, oacc[dt], 0, 0, 0);
            }
        }
    }
    // ---- epilogue ----
    rs += __shfl_xor(rs, 32);
    rsL += __shfl_xor(rsL, 32);
    // exp band in place; slot 63 = rsL (pairs embS[0] = left bucket)
    float sumBand = 0.f;
#pragma unroll
    for (int c = 0; c < 4; ++c) {
        const int kb = 32 * h + 8 * c;
        half8 bv = *(const half8*)&band[tl * 72 + kb];
        half8 ev;
#pragma unroll
        for (int j = 0; j < 8; ++j) {
            const int k = kb + j;
            float v;
            if (k == 63) v = rsL;
            else { v = __expf((float)bv[j]); sumBand += v; }
            ev[j] = (f16)v;
        }
        *(half8*)&band[tl * 72 + kb] = ev;
    }
    sumBand += __shfl_xor(sumBand, 32);
    const float sumR = rs - rsL - sumBand;
    // stage eSt[d][k] = embS[(k==63?0:k+1)][d] swizzled into Kt[0]
    // (last compute tile used buffers [1]; Kt[0] is free without a barrier)
    for (int idx = tid; idx < 512; idx += 256) {
        const int d = idx >> 3, p = idx & 7, g = p ^ (d & 7);
        half8 hv;
#pragma unroll
        for (int j = 0; j < 8; ++j) {
            const int k = g * 8 + j;
            hv[j] = (f16)embS[((k == 63) ? 0 : (k + 1)) * 64 + d];
        }
        *(half8*)&Kt[0][d * 64 + p * 8] = hv;
    }
    __syncthreads();
    // O += eSt @ Pband^T   (A = ef rows = d, B = pf cols = t)
#pragma unroll
    for (int ks = 0; ks < 4; ++ks) {
        half8 pf = *(const half8*)&band[tl * 72 + 16 * ks + 8 * h];
#pragma unroll
        for (int dt = 0; dt < 2; ++dt) {
            const int row = tl32 + 32 * dt;
            const int p = (2 * ks + h) ^ (row & 7);
            half8 ef = *(const half8*)&Kt[0][row * 64 + p * 8];
            oacc[dt] = __builtin_amdgcn_mfma_f32_32x32x16_f16(
                ef, pf, oacc[dt], 0, 0, 0);
        }
    }
    __syncthreads();   // band (Pband) reads done before O-transpose overwrite
    // O (row=d, col=own t) -> band space [tl][d], then coalesced global store
    const float inv = 1.0f / rs;
#pragma unroll
    for (int dt = 0; dt < 2; ++dt)
#pragma unroll
        for (int r = 0; r < 16; ++r) {
            const int d = (r & 3) + 8 * (r >> 2) + 4 * h + 32 * dt;
            band[tl * 72 + d] = (f16)((oacc[dt][r] + sumR * e64s[d]) * inv);
        }
    __syncthreads();
    const int b = bh >> 4, hh = bh & 15;
    const int row = tid >> 1, cb = (tid & 1) * 32;
    f16* dst = heads16 + ((size_t)(b * 1024 + t0 + row) * 1024) + hh * 64 + cb;
#pragma unroll
    for (int c = 0; c < 4; ++c)
        *(half8*)&dst[c * 8] = *(const half8*)&band[row * 72 + cb + c * 8];
}

// ---------------------------------------------------------------------------
extern "C" void kernel_launch(void* const* d_in, const int* in_sizes, int n_in,
                              void* d_out, int out_size, void* d_ws, size_t ws_size,
                              hipStream_t stream) {
    const float* query = (const float*)d_in[0];
    const float* value = (const float*)d_in[1];
    const float* WQ   = (const float*)d_in[2];
    const float* WK   = (const float*)d_in[3];
    const float* WV   = (const float*)d_in[4];
    const float* WO   = (const float*)d_in[5];
    const float* embQ = (const float*)d_in[6];
    const float* embS = (const float*)d_in[7];
    float* out = (float*)d_out;

    f16* w0    = (f16*)d_ws;
    f16* q16   = w0;                 // 4,194,304 h (+ v16 contiguous)
    f16* v16   = w0 + 4194304;       // 4,194,304 h
    f16* Wt16  = w0 + 8388608;       // 3,145,728 h
    f16* WOt16 = w0 + 11534336;      // 1,048,576 h
    f16* q16a  = w0 + 12582912;      // 4,194,304 h (qW/8)
    f16* k16   = w0 + 16777216;      // 4,194,304 h
    f16* vt16  = w0 + 20971520;      // 4,194,304 h (V transposed [bh][d][t])
    f16* h16   = w0 + 25165824;      // 4,194,304 h  (end: 58.7 MB)

    prep<<<9216, 256, 0, stream>>>(query, value, WQ, WK, WV, WO,
                                   q16, Wt16, WOt16);
    mfma_gemm<0, 128, true><<<768, 256, 0, stream>>>(
        q16, v16, Wt16, nullptr, q16a, k16, vt16);
    attn_kernel<<<dim3(64, 8), 256, 0, stream>>>(q16a, k16, vt16, embQ, embS, h16);
    mfma_gemm<1, 64, true><<<512, 256, 0, stream>>>(
        h16, h16, WOt16, out, nullptr, nullptr, nullptr);
}

// Round 9
// 201.698 us; speedup vs baseline: 1.0894x; 1.0259x over previous
//
#include <hip/hip_runtime.h>
#include <math.h>

// Problem constants: B=4, T=1024, D_MODEL=1024, H=16, DK=64, R=65 (2*32+1)
//
// Pipeline (4 launches):
//   prep                  : fused cast_qv + transpose_cast_w + transpose_cast_wo
//   mfma_gemm<0,128,true> : fp16 outputs q16a (=qW*log2e/8), k16, vt16 (V
//                           transposed; NOW written via LDS-transpose +
//                           coalesced half8 stores). Dbuf + XCD swizzle.
//   attn_kernel           : v3 structure (proven 52.5 us) + exp2-domain
//                           softmax (q16a pre-scaled by log2e -> exp2f, no
//                           v_mul) + s_setprio around MFMA clusters (T5,
//                           m191: +4-7% on attn's independent-block regime).
//   mfma_gemm<1,64,true>  : out fp32 = heads16 @ W_O^T, XCD-swizzled flat grid
//
// MFMA orientation convention (verified r3-r7 + m74/m101 C/D map):
//   mfma(A, B, C): A rows on lane&31, B cols on lane&31,
//   D: col = lane&31, row = (reg&3) + 8*(reg>>2) + 4*(lane>>5).
//   S^T : mfma(kf, qf) -> row=s, col=t
//   PV  : mfma(vf, pf) -> row=d, col=t   (pf MUST be the B operand)
//   band: mfma(ef, pf) -> row=d, col=t

typedef _Float16 f16;
typedef f16 half8 __attribute__((ext_vector_type(8)));
typedef f16 half4v __attribute__((ext_vector_type(4)));
typedef float f32x4 __attribute__((ext_vector_type(4)));
typedef float f32x16 __attribute__((ext_vector_type(16)));

// ---------------------------------------------------------------------------
// prep: bx<8192 -> cast q,v to fp16; 8192..8959 -> W_{Q,K,V} transpose+cast;
// 8960..9215 -> W_O transpose+cast.
// ---------------------------------------------------------------------------
__global__ __launch_bounds__(256) void prep(
    const float* __restrict__ q, const float* __restrict__ v,
    const float* __restrict__ W0, const float* __restrict__ W1,
    const float* __restrict__ W2, const float* __restrict__ WO,
    f16* __restrict__ q16, f16* __restrict__ Wt16, f16* __restrict__ WOt16) {
    __shared__ float tile[64][65];
    const int bx = blockIdx.x;
    const int t = threadIdx.x;
    if (bx < 8192) {
        int i = (bx * 256 + t) * 4;
        const float* s = (i < 4194304) ? (q + i) : (v + (i - 4194304));
        float4 x = *(const float4*)s;
        half4v h = {(f16)x.x, (f16)x.y, (f16)x.z, (f16)x.w};
        *(half4v*)&q16[i] = h;
        return;
    }
    const int c = t & 63, r4 = t >> 6;
    const int n = t >> 2, kc = (t & 3) * 16;
    if (bx < 8960) {
        const int idx = bx - 8192;
        const int z = idx >> 4, k0 = (idx & 15) * 64;
        const float* src = ((z < 16) ? W0 : (z < 32) ? W1 : W2) + (size_t)(z & 15) * 65536;
        f16* out = Wt16 + (size_t)z * 65536;
#pragma unroll
        for (int p = 0; p < 16; ++p)
            tile[r4 + p * 4][c] = src[(size_t)(k0 + r4 + p * 4) * 64 + c];
        __syncthreads();
        f16 buf[16];
#pragma unroll
        for (int i = 0; i < 16; ++i) buf[i] = (f16)tile[kc + i][n];
        *(half8*)&out[(size_t)n * 1024 + k0 + kc] = *(half8*)&buf[0];
        *(half8*)&out[(size_t)n * 1024 + k0 + kc + 8] = *(half8*)&buf[8];
        return;
    }
    {
        const int idx = bx - 8960;
        const int k0 = (idx & 15) * 64, n0 = (idx >> 4) * 64;
#pragma unroll
        for (int p = 0; p < 16; ++p)
            tile[r4 + p * 4][c] = WO[(size_t)(k0 + r4 + p * 4) * 1024 + n0 + c];
        __syncthreads();
        f16 buf[16];
#pragma unroll
        for (int i = 0; i < 16; ++i) buf[i] = (f16)tile[kc + i][n];
        *(half8*)&WOt16[(size_t)(n0 + n) * 1024 + k0 + kc] = *(half8*)&buf[0];
        *(half8*)&WOt16[(size_t)(n0 + n) * 1024 + k0 + kc + 8] = *(half8*)&buf[8];
    }
}

// ---------------------------------------------------------------------------
// fp16 MFMA GEMM, 128xNT tile (NT = 128 or 64), single-barrier double-buffered
// staging, FLAT grid with bijective XCD swizzle. MODE 0: write q16a
// (acc*log2e/8), k16, vt16 (transposed, via LDS-transpose coalesced path),
// NX=24. MODE 1: write fp32 C, NX=16.
// ---------------------------------------------------------------------------
template <int MODE, int NT, bool DBUF>
__global__ __launch_bounds__(256) void mfma_gemm(
    const f16* __restrict__ Aq, const f16* __restrict__ Av,
    const f16* __restrict__ Bt, float* __restrict__ C,
    f16* __restrict__ oQ, f16* __restrict__ oK, f16* __restrict__ oVt) {
    constexpr int K = 1024;
    constexpr int NI = NT / 32;                 // n-frags per wave
    constexpr int LDSZ = (128 + NT) * 64;       // halves per buffer
    constexpr int NX = (MODE == 0) ? 24 : 16;   // n-tiles in grid
    const int f = blockIdx.x;
    const int cpx = gridDim.x >> 3;             // nwg/8 (both grids %8==0)
    const int swz = (f & 7) * cpx + (f >> 3);
    const int n0 = (swz % NX) * NT;
    const int m0 = (swz / NX) * 128;
    const f16* Abase = (MODE == 0) ? ((n0 < 1024) ? Aq : Av) : Aq;

    __shared__ f16 lds[LDSZ * (DBUF ? 2 : 1)];

    const int tid = threadIdx.x;
    const int l = tid & 63, wv = tid >> 6;
    const int rseg = l >> 3;
    const int g = (l & 7) ^ rseg;
    const bool isA = (wv < 2);
    const int rowBase = isA ? (wv & 1) * 64 : (wv & 1) * (NT / 2);
    const int nLoads = isA ? 8 : (NT / 16);
    const f16* gSrc = isA ? (Abase + (size_t)m0 * K) : (Bt + (size_t)n0 * K);
    const f16* gLane = gSrc + (size_t)(rowBase + rseg) * K + g * 8;
    const int ldsRow0 = (isA ? 0 : 128) + rowBase;

    const int fr = l & 15, fq = l >> 4, sw = fr & 7;
    const int mi2 = wv & 1, ni2 = wv >> 1;
    int aOff[NI], bOff[4];
#pragma unroll
    for (int i = 0; i < 4; ++i) bOff[i] = (mi2 * 64 + i * 16 + fr) * 128;
#pragma unroll
    for (int i = 0; i < NI; ++i)
        aOff[i] = (128 + ni2 * (NT / 2) + i * 16 + fr) * 128;

    f32x4 acc[4][NI];
#pragma unroll
    for (int i = 0; i < 4; ++i)
#pragma unroll
        for (int j = 0; j < NI; ++j) acc[i][j] = {0.f, 0.f, 0.f, 0.f};

    auto issue = [&](int k0, int buf) {
        f16* dst = lds + (buf ? LDSZ : 0);
#pragma unroll 8
        for (int i = 0; i < nLoads; ++i) {
            const f16* src = gLane + (size_t)i * 8 * K + k0;
            __builtin_amdgcn_global_load_lds(
                (const __attribute__((address_space(1))) unsigned int*)src,
                (__attribute__((address_space(3))) unsigned int*)
                    &dst[(ldsRow0 + i * 8) * 64], 16, 0, 0);
        }
    };

    if (DBUF) issue(0, 0);
    int it = 0;
    for (int k0 = 0; k0 < K; k0 += 64, ++it) {
        if (!DBUF) issue(k0, 0);
        __syncthreads();
        if (DBUF && k0 + 64 < K) issue(k0 + 64, (it + 1) & 1);
        const char* lp = (const char*)lds + (DBUF ? (it & 1) * (LDSZ * 2) : 0);
#pragma unroll
        for (int kk = 0; kk < 2; ++kk) {
            const int glq = kk * 4 + fq;
            const int sgl = (glq ^ sw) * 16;
            half8 aF[NI], bF[4];
#pragma unroll
            for (int i = 0; i < NI; ++i)
                aF[i] = *(const half8*)(lp + aOff[i] + sgl);
#pragma unroll
            for (int i = 0; i < 4; ++i)
                bF[i] = *(const half8*)(lp + bOff[i] + sgl);
#pragma unroll
            for (int mi = 0; mi < 4; ++mi)
#pragma unroll
                for (int ni = 0; ni < NI; ++ni)
                    acc[mi][ni] = __builtin_amdgcn_mfma_f32_16x16x32_f16(
                        aF[ni], bF[mi], acc[mi][ni], 0, 0, 0);
        }
        if (!DBUF) __syncthreads();
    }
    // ---- MODE 0, vt16 blocks (n0 >= 2048, block-uniform): LDS transpose ----
    if (MODE == 0 && n0 >= 2048) {
        __syncthreads();            // all K-loop LDS reads done; lds reusable
        f16* Tr = lds;              // [128 n_local][136] padded f16
#pragma unroll
        for (int mi = 0; mi < 4; ++mi) {
            const int ml = mi2 * 64 + mi * 16 + fr;
#pragma unroll
            for (int ni = 0; ni < NI; ++ni) {
                const int nl = ni2 * (NT / 2) + ni * 16 + 4 * fq;
                f32x4 a = acc[mi][ni];
#pragma unroll
                for (int r = 0; r < 4; ++r)
                    Tr[(nl + r) * 136 + ml] = (f16)a[r];
            }
        }
        __syncthreads();
        const int b = m0 >> 10, t0m = m0 & 1023;
        const int hh = (n0 >> 6) & 15;       // head for n_local 0..63
        const int row = tid >> 1, cb = (tid & 1) * 64;
        const size_t bh = (size_t)(b * 16 + hh + (row >> 6));
        const int d = row & 63;
        f16* dst = oVt + bh * 65536 + (size_t)d * 1024 + t0m + cb;
#pragma unroll
        for (int c = 0; c < 8; ++c)
            *(half8*)&dst[c * 8] = *(const half8*)&Tr[row * 136 + cb + c * 8];
        return;
    }
#pragma unroll
    for (int mi = 0; mi < 4; ++mi) {
        const int m = m0 + mi2 * 64 + mi * 16 + fr;
#pragma unroll
        for (int ni = 0; ni < NI; ++ni) {
            const int n = n0 + ni2 * (NT / 2) + ni * 16 + 4 * fq;
            if (MODE == 1) {
                *(f32x4*)(C + (size_t)m * 1024 + n) = acc[mi][ni];
            } else {
                const int w = n >> 10, h = (n >> 6) & 15, d = n & 63;
                const int b = m >> 10, t = m & 1023;
                const size_t bh = (size_t)(b * 16 + h);
                f32x4 a = acc[mi][ni];
                if (w == 0) {
                    // scale = log2(e)/8: exp2-domain softmax in attn
                    const float sc = 0.18033688f;
                    half4v hv = {(f16)(a[0] * sc), (f16)(a[1] * sc),
                                 (f16)(a[2] * sc), (f16)(a[3] * sc)};
                    *(half4v*)&oQ[bh * 65536 + (size_t)t * 64 + d] = hv;
                } else {
                    half4v hv = {(f16)a[0], (f16)a[1], (f16)a[2], (f16)a[3]};
                    *(half4v*)&oK[bh * 65536 + (size_t)t * 64 + d] = hv;
                }
            }
        }
    }
}

// ---------------------------------------------------------------------------
// MFMA flash attention (v3 structure + exp2 + setprio): 32x32x16 MFMAs,
// block = (bh, 128-row q-tile), 4 waves x 32 t. NO-max softmax in the exp2
// domain (q16a pre-scaled by log2e/8 -> exp2f, no v_mul per element).
// P in regs (shfl_xor(32) exchange). K/V staged unpadded+XOR-swizzled via
// global_load_lds into DOUBLE buffers: one barrier per iter.
// ---------------------------------------------------------------------------
__global__ __launch_bounds__(256, 2) void attn_kernel(
    const f16* __restrict__ q16a, const f16* __restrict__ k16,
    const f16* __restrict__ vt16, const float* __restrict__ embQ,
    const float* __restrict__ embS, f16* __restrict__ heads16) {
    const int bh = blockIdx.x;
    const int t0 = blockIdx.y * 128;
    const f16* qg = q16a + (size_t)bh * 65536;
    const f16* kg = k16 + (size_t)bh * 65536;
    const f16* vg = vt16 + (size_t)bh * 65536;

    __shared__ f16 Kt[2][4096];     // [s][d] 64x64, swizzled; Kt[0] = eSt at end
    __shared__ f16 Vt[2][4096];     // [d][s] 64x64, swizzled
    __shared__ f16 qEl[66 * 136];   // [r][tl] r=0..64, tl=0..127
    __shared__ f16 band[128 * 72];  // [tl][k] raw scores; also embQ staging
                                    // (prologue) and O transpose (epilogue)
    __shared__ float e64s[64];

    const int tid = threadIdx.x;
    const int wv = tid >> 6, lane = tid & 63;
    const int tl32 = lane & 31, h = lane >> 5;
    const int tl = wv * 32 + tl32;       // 0..127
    const int tg = t0 + tl;

    auto stageKV = [&](int j0, int buf) {
#pragma unroll
        for (int i = 0; i < 2; ++i) {
            const int rt = wv * 16 + i * 8 + (lane >> 3);
            const int g = (lane & 7) ^ (rt & 7);
            __builtin_amdgcn_global_load_lds(
                (const __attribute__((address_space(1))) unsigned int*)
                    (kg + (size_t)(j0 + rt) * 64 + g * 8),
                (__attribute__((address_space(3))) unsigned int*)
                    &Kt[buf][(wv * 16 + i * 8) * 64], 16, 0, 0);
            __builtin_amdgcn_global_load_lds(
                (const __attribute__((address_space(1))) unsigned int*)
                    (vg + (size_t)rt * 1024 + j0 + g * 8),
                (__attribute__((address_space(3))) unsigned int*)
                    &Vt[buf][(wv * 16 + i * 8) * 64], 16, 0, 0);
        }
    };

    // Q B-frags first (oldest vmcnt slots), then preload tile 0 -> buffer 0.
    half8 qf[4];
#pragma unroll
    for (int ks = 0; ks < 4; ++ks)
        qf[ks] = *(const half8*)&qg[(size_t)tg * 64 + (2 * ks + h) * 8];
    stageKV(0, 0);

    // ---- stage embQ swizzled [row][64] into band space (rows 65..95 zero) --
    f16* embQs = band;
    for (int idx = tid; idx < 768; idx += 256) {
        const int row = idx >> 3, p = idx & 7, g = p ^ (row & 7);
        half8 hv;
        if (row < 65) {
            const float* s = embQ + row * 64 + g * 8;
#pragma unroll
            for (int j = 0; j < 8; ++j) hv[j] = (f16)s[j];
        } else {
#pragma unroll
            for (int j = 0; j < 8; ++j) hv[j] = (f16)0.f;
        }
        *(half8*)&embQs[row * 64 + p * 8] = hv;
    }
    __syncthreads();
    // ---- fused qE: qEl[r][tl] = embQ[r] . Q[tg]  (D: row=r, col=t) ----
    {
        f32x16 qacc[3];
#pragma unroll
        for (int mt = 0; mt < 3; ++mt)
#pragma unroll
            for (int r = 0; r < 16; ++r) qacc[mt][r] = 0.f;
#pragma unroll
        for (int ks = 0; ks < 4; ++ks)
#pragma unroll
            for (int mt = 0; mt < 3; ++mt) {
                const int row = tl32 + 32 * mt;
                const int p = (2 * ks + h) ^ (row & 7);
                half8 ef = *(const half8*)&embQs[row * 64 + p * 8];
                qacc[mt] = __builtin_amdgcn_mfma_f32_32x32x16_f16(
                    ef, qf[ks], qacc[mt], 0, 0, 0);
            }
        __syncthreads();   // embQs reads done; band space reusable
#pragma unroll
        for (int mt = 0; mt < 3; ++mt)
#pragma unroll
            for (int r = 0; r < 16; ++r) {
                const int rr = (r & 3) + 8 * (r >> 2) + 4 * h + 32 * mt;
                if (rr < 65) qEl[rr * 136 + tl] = (f16)qacc[mt][r];
            }
    }
    // init band to -1e4 (exp2 -> 0)
    for (int idx = tid; idx < 1152; idx += 256) {
        half8 hv;
#pragma unroll
        for (int j = 0; j < 8; ++j) hv[j] = (f16)(-1.0e4f);
        *(half8*)&band[idx * 8] = hv;
    }
    if (tid < 64) e64s[tid] = embS[64 * 64 + tid];
    __syncthreads();
    const float qE0 = (float)qEl[tl];
    const float qE64 = (float)qEl[64 * 136 + tl];

    float rs = 0.f, rsL = 0.f;
    f32x16 oacc[2];
#pragma unroll
    for (int dt = 0; dt < 2; ++dt)
#pragma unroll
        for (int r = 0; r < 16; ++r) oacc[dt][r] = 0.f;

    for (int jt = 0; jt < 16; ++jt) {
        const int j0 = jt * 64;
        __syncthreads();   // tile jt staged; prev compute's LDS reads done
        if (jt < 15) stageKV(j0 + 64, (jt + 1) & 1);
        const f16* Ktc = Kt[jt & 1];
        const f16* Vtc = Vt[jt & 1];
        // S^T = K @ Q^T : D[m=s][n=t], col = t(lane&31)
        f32x16 sacc[2];
#pragma unroll
        for (int mt = 0; mt < 2; ++mt)
#pragma unroll
            for (int r = 0; r < 16; ++r) sacc[mt][r] = 0.f;
        __builtin_amdgcn_s_setprio(1);
#pragma unroll
        for (int ks = 0; ks < 4; ++ks)
#pragma unroll
            for (int mt = 0; mt < 2; ++mt) {
                const int row = tl32 + 32 * mt;
                const int p = (2 * ks + h) ^ (row & 7);
                half8 kf = *(const half8*)&Ktc[row * 64 + p * 8];
                sacc[mt] = __builtin_amdgcn_mfma_f32_32x32x16_f16(
                    kf, qf[ks], sacc[mt], 0, 0, 0);
            }
        __builtin_amdgcn_s_setprio(0);
        // bias + exp2 (+band capture on diagonal tiles) — log2e domain
        const int dj = j0 - t0;
        if (dj <= -128 || dj >= 192) {
            const float bias = (dj < 0) ? qE0 : qE64;
            float ts = 0.f;
#pragma unroll
            for (int mt = 0; mt < 2; ++mt)
#pragma unroll
                for (int r = 0; r < 16; ++r) {
                    float pe = exp2f(sacc[mt][r] + bias);
                    sacc[mt][r] = pe; ts += pe;
                }
            rs += ts;
            if (dj < 0) rsL += ts;
        } else {
#pragma unroll
            for (int mt = 0; mt < 2; ++mt)
#pragma unroll
                for (int r = 0; r < 16; ++r) {
                    const int sg = j0 + 32 * mt + (r & 3) + 8 * (r >> 2) + 4 * h;
                    const int ds = sg - tg;
                    const int dc = ds < -32 ? -32 : (ds > 32 ? 32 : ds);
                    float v = sacc[mt][r] + (float)qEl[(dc + 32) * 136 + tl];
                    if (ds >= -31 && ds <= 31) band[tl * 72 + ds + 31] = (f16)v;
                    float pe = exp2f(v);
                    sacc[mt][r] = pe; rs += pe;
                    if (ds <= -32) rsL += pe;
                }
        }
        // PV: O[d][t] += V^T @ P^T ; P B-frag via half-wave shfl exchange
#pragma unroll
        for (int ks = 0; ks < 4; ++ks) {
            const int mtile = ks >> 1, rb = (ks & 1) * 8;
            float ex[4];
#pragma unroll
            for (int c = 0; c < 4; ++c) {
                float send = (h == 0) ? sacc[mtile][rb + 4 + c]
                                      : sacc[mtile][rb + c];
                ex[c] = __shfl_xor(send, 32);
            }
            half8 pf;
#pragma unroll
            for (int j = 0; j < 4; ++j)
                pf[j] = (f16)((h == 0) ? sacc[mtile][rb + j] : ex[j]);
#pragma unroll
            for (int j = 0; j < 4; ++j)
                pf[4 + j] = (f16)((h == 0) ? ex[j] : sacc[mtile][rb + 4 + j]);
            __builtin_amdgcn_s_setprio(1);
#pragma unroll
            for (int dt = 0; dt < 2; ++dt) {
                const int row = tl32 + 32 * dt;
                const int p = (2 * ks + h) ^ (row & 7);
                half8 vf = *(const half8*)&Vtc[row * 64 + p * 8];
                // A = vf (rows = d), B = pf (cols = t)  ->  D[row=d][col=t]
                oacc[dt] = __builtin_amdgcn_mfma_f32_32x32x16_f16(
                    vf, pf, oacc[dt], 0, 0, 0);
            }
            __builtin_amdgcn_s_setprio(0);
        }
    }
    // ---- epilogue ----
    rs += __shfl_xor(rs, 32);
    rsL += __shfl_xor(rsL, 32);
    // exp2 band in place; slot 63 = rsL (pairs embS[0] = left bucket)
    float sumBand = 0.f;
#pragma unroll
    for (int c = 0; c < 4; ++c) {
        const int kb = 32 * h + 8 * c;
        half8 bv = *(const half8*)&band[tl * 72 + kb];
        half8 ev;
#pragma unroll
        for (int j = 0; j < 8; ++j) {
            const int k = kb + j;
            float v;
            if (k == 63) v = rsL;
            else { v = exp2f((float)bv[j]); sumBand += v; }
            ev[j] = (f16)v;
        }
        *(half8*)&band[tl * 72 + kb] = ev;
    }
    sumBand += __shfl_xor(sumBand, 32);
    const float sumR = rs - rsL - sumBand;
    // stage eSt[d][k] = embS[(k==63?0:k+1)][d] swizzled into Kt[0]
    // (last compute tile used buffers [1]; Kt[0] is free without a barrier)
    for (int idx = tid; idx < 512; idx += 256) {
        const int d = idx >> 3, p = idx & 7, g = p ^ (d & 7);
        half8 hv;
#pragma unroll
        for (int j = 0; j < 8; ++j) {
            const int k = g * 8 + j;
            hv[j] = (f16)embS[((k == 63) ? 0 : (k + 1)) * 64 + d];
        }
        *(half8*)&Kt[0][d * 64 + p * 8] = hv;
    }
    __syncthreads();
    // O += eSt @ Pband^T   (A = ef rows = d, B = pf cols = t)
#pragma unroll
    for (int ks = 0; ks < 4; ++ks) {
        half8 pf = *(const half8*)&band[tl * 72 + 16 * ks + 8 * h];
#pragma unroll
        for (int dt = 0; dt < 2; ++dt) {
            const int row = tl32 + 32 * dt;
            const int p = (2 * ks + h) ^ (row & 7);
            half8 ef = *(const half8*)&Kt[0][row * 64 + p * 8];
            oacc[dt] = __builtin_amdgcn_mfma_f32_32x32x16_f16(
                ef, pf, oacc[dt], 0, 0, 0);
        }
    }
    __syncthreads();   // band (Pband) reads done before O-transpose overwrite
    // O (row=d, col=own t) -> band space [tl][d], then coalesced global store
    const float inv = 1.0f / rs;
#pragma unroll
    for (int dt = 0; dt < 2; ++dt)
#pragma unroll
        for (int r = 0; r < 16; ++r) {
            const int d = (r & 3) + 8 * (r >> 2) + 4 * h + 32 * dt;
            band[tl * 72 + d] = (f16)((oacc[dt][r] + sumR * e64s[d]) * inv);
        }
    __syncthreads();
    const int b = bh >> 4, hh = bh & 15;
    const int row = tid >> 1, cb = (tid & 1) * 32;
    f16* dst = heads16 + ((size_t)(b * 1024 + t0 + row) * 1024) + hh * 64 + cb;
#pragma unroll
    for (int c = 0; c < 4; ++c)
        *(half8*)&dst[c * 8] = *(const half8*)&band[row * 72 + cb + c * 8];
}

// ---------------------------------------------------------------------------
extern "C" void kernel_launch(void* const* d_in, const int* in_sizes, int n_in,
                              void* d_out, int out_size, void* d_ws, size_t ws_size,
                              hipStream_t stream) {
    const float* query = (const float*)d_in[0];
    const float* value = (const float*)d_in[1];
    const float* WQ   = (const float*)d_in[2];
    const float* WK   = (const float*)d_in[3];
    const float* WV   = (const float*)d_in[4];
    const float* WO   = (const float*)d_in[5];
    const float* embQ = (const float*)d_in[6];
    const float* embS = (const float*)d_in[7];
    float* out = (float*)d_out;

    f16* w0    = (f16*)d_ws;
    f16* q16   = w0;                 // 4,194,304 h (+ v16 contiguous)
    f16* v16   = w0 + 4194304;       // 4,194,304 h
    f16* Wt16  = w0 + 8388608;       // 3,145,728 h
    f16* WOt16 = w0 + 11534336;      // 1,048,576 h
    f16* q16a  = w0 + 12582912;      // 4,194,304 h (qW*log2e/8)
    f16* k16   = w0 + 16777216;      // 4,194,304 h
    f16* vt16  = w0 + 20971520;      // 4,194,304 h (V transposed [bh][d][t])
    f16* h16   = w0 + 25165824;      // 4,194,304 h  (end: 58.7 MB)

    prep<<<9216, 256, 0, stream>>>(query, value, WQ, WK, WV, WO,
                                   q16, Wt16, WOt16);
    mfma_gemm<0, 128, true><<<768, 256, 0, stream>>>(
        q16, v16, Wt16, nullptr, q16a, k16, vt16);
    attn_kernel<<<dim3(64, 8), 256, 0, stream>>>(q16a, k16, vt16, embQ, embS, h16);
    mfma_gemm<1, 64, true><<<512, 256, 0, stream>>>(
        h16, h16, WOt16, out, nullptr, nullptr, nullptr);
}

// Round 10
// 196.685 us; speedup vs baseline: 1.1172x; 1.0255x over previous
//
#include <hip/hip_runtime.h>
#include <math.h>

// Problem constants: B=4, T=1024, D_MODEL=1024, H=16, DK=64, R=65 (2*32+1)
//
// Pipeline (4 launches):
//   prep                  : fused cast_qv + transpose_cast_w + transpose_cast_wo
//   mfma_gemm<0,128,true> : fp16 outputs q16a (=qW/8), k16, vt16 (V transposed
//                           via LDS-transpose + coalesced half8 stores — the
//                           r9-proven ~21us win). Dbuf + XCD swizzle.
//   attn_kernel           : v3 VERBATIM (proven 52.4 us fingerprint): __expf,
//                           no setprio. r9 lesson: exp2f lowers to PRECISE
//                           OCML (more VALU, +4 VGPR), and setprio hurts in
//                           barrier-lockstep blocks (m190 regime) — both
//                           reverted.
//   mfma_gemm<1,64,true>  : out fp32 = heads16 @ W_O^T, XCD-swizzled flat grid
//
// MFMA orientation convention (verified r3-r7 + m74/m101 C/D map):
//   mfma(A, B, C): A rows on lane&31, B cols on lane&31,
//   D: col = lane&31, row = (reg&3) + 8*(reg>>2) + 4*(lane>>5).
//   S^T : mfma(kf, qf) -> row=s, col=t
//   PV  : mfma(vf, pf) -> row=d, col=t   (pf MUST be the B operand)
//   band: mfma(ef, pf) -> row=d, col=t

typedef _Float16 f16;
typedef f16 half8 __attribute__((ext_vector_type(8)));
typedef f16 half4v __attribute__((ext_vector_type(4)));
typedef float f32x4 __attribute__((ext_vector_type(4)));
typedef float f32x16 __attribute__((ext_vector_type(16)));

// ---------------------------------------------------------------------------
// prep: bx<8192 -> cast q,v to fp16; 8192..8959 -> W_{Q,K,V} transpose+cast;
// 8960..9215 -> W_O transpose+cast.
// ---------------------------------------------------------------------------
__global__ __launch_bounds__(256) void prep(
    const float* __restrict__ q, const float* __restrict__ v,
    const float* __restrict__ W0, const float* __restrict__ W1,
    const float* __restrict__ W2, const float* __restrict__ WO,
    f16* __restrict__ q16, f16* __restrict__ Wt16, f16* __restrict__ WOt16) {
    __shared__ float tile[64][65];
    const int bx = blockIdx.x;
    const int t = threadIdx.x;
    if (bx < 8192) {
        int i = (bx * 256 + t) * 4;
        const float* s = (i < 4194304) ? (q + i) : (v + (i - 4194304));
        float4 x = *(const float4*)s;
        half4v h = {(f16)x.x, (f16)x.y, (f16)x.z, (f16)x.w};
        *(half4v*)&q16[i] = h;
        return;
    }
    const int c = t & 63, r4 = t >> 6;
    const int n = t >> 2, kc = (t & 3) * 16;
    if (bx < 8960) {
        const int idx = bx - 8192;
        const int z = idx >> 4, k0 = (idx & 15) * 64;
        const float* src = ((z < 16) ? W0 : (z < 32) ? W1 : W2) + (size_t)(z & 15) * 65536;
        f16* out = Wt16 + (size_t)z * 65536;
#pragma unroll
        for (int p = 0; p < 16; ++p)
            tile[r4 + p * 4][c] = src[(size_t)(k0 + r4 + p * 4) * 64 + c];
        __syncthreads();
        f16 buf[16];
#pragma unroll
        for (int i = 0; i < 16; ++i) buf[i] = (f16)tile[kc + i][n];
        *(half8*)&out[(size_t)n * 1024 + k0 + kc] = *(half8*)&buf[0];
        *(half8*)&out[(size_t)n * 1024 + k0 + kc + 8] = *(half8*)&buf[8];
        return;
    }
    {
        const int idx = bx - 8960;
        const int k0 = (idx & 15) * 64, n0 = (idx >> 4) * 64;
#pragma unroll
        for (int p = 0; p < 16; ++p)
            tile[r4 + p * 4][c] = WO[(size_t)(k0 + r4 + p * 4) * 1024 + n0 + c];
        __syncthreads();
        f16 buf[16];
#pragma unroll
        for (int i = 0; i < 16; ++i) buf[i] = (f16)tile[kc + i][n];
        *(half8*)&WOt16[(size_t)(n0 + n) * 1024 + k0 + kc] = *(half8*)&buf[0];
        *(half8*)&WOt16[(size_t)(n0 + n) * 1024 + k0 + kc + 8] = *(half8*)&buf[8];
    }
}

// ---------------------------------------------------------------------------
// fp16 MFMA GEMM, 128xNT tile (NT = 128 or 64), single-barrier double-buffered
// staging, FLAT grid with bijective XCD swizzle. MODE 0: write q16a (acc/8),
// k16, vt16 (transposed, via LDS-transpose coalesced path), NX=24.
// MODE 1: write fp32 C, NX=16.
// ---------------------------------------------------------------------------
template <int MODE, int NT, bool DBUF>
__global__ __launch_bounds__(256) void mfma_gemm(
    const f16* __restrict__ Aq, const f16* __restrict__ Av,
    const f16* __restrict__ Bt, float* __restrict__ C,
    f16* __restrict__ oQ, f16* __restrict__ oK, f16* __restrict__ oVt) {
    constexpr int K = 1024;
    constexpr int NI = NT / 32;                 // n-frags per wave
    constexpr int LDSZ = (128 + NT) * 64;       // halves per buffer
    constexpr int NX = (MODE == 0) ? 24 : 16;   // n-tiles in grid
    const int f = blockIdx.x;
    const int cpx = gridDim.x >> 3;             // nwg/8 (both grids %8==0)
    const int swz = (f & 7) * cpx + (f >> 3);
    const int n0 = (swz % NX) * NT;
    const int m0 = (swz / NX) * 128;
    const f16* Abase = (MODE == 0) ? ((n0 < 1024) ? Aq : Av) : Aq;

    __shared__ f16 lds[LDSZ * (DBUF ? 2 : 1)];

    const int tid = threadIdx.x;
    const int l = tid & 63, wv = tid >> 6;
    const int rseg = l >> 3;
    const int g = (l & 7) ^ rseg;
    const bool isA = (wv < 2);
    const int rowBase = isA ? (wv & 1) * 64 : (wv & 1) * (NT / 2);
    const int nLoads = isA ? 8 : (NT / 16);
    const f16* gSrc = isA ? (Abase + (size_t)m0 * K) : (Bt + (size_t)n0 * K);
    const f16* gLane = gSrc + (size_t)(rowBase + rseg) * K + g * 8;
    const int ldsRow0 = (isA ? 0 : 128) + rowBase;

    const int fr = l & 15, fq = l >> 4, sw = fr & 7;
    const int mi2 = wv & 1, ni2 = wv >> 1;
    int aOff[NI], bOff[4];
#pragma unroll
    for (int i = 0; i < 4; ++i) bOff[i] = (mi2 * 64 + i * 16 + fr) * 128;
#pragma unroll
    for (int i = 0; i < NI; ++i)
        aOff[i] = (128 + ni2 * (NT / 2) + i * 16 + fr) * 128;

    f32x4 acc[4][NI];
#pragma unroll
    for (int i = 0; i < 4; ++i)
#pragma unroll
        for (int j = 0; j < NI; ++j) acc[i][j] = {0.f, 0.f, 0.f, 0.f};

    auto issue = [&](int k0, int buf) {
        f16* dst = lds + (buf ? LDSZ : 0);
#pragma unroll 8
        for (int i = 0; i < nLoads; ++i) {
            const f16* src = gLane + (size_t)i * 8 * K + k0;
            __builtin_amdgcn_global_load_lds(
                (const __attribute__((address_space(1))) unsigned int*)src,
                (__attribute__((address_space(3))) unsigned int*)
                    &dst[(ldsRow0 + i * 8) * 64], 16, 0, 0);
        }
    };

    if (DBUF) issue(0, 0);
    int it = 0;
    for (int k0 = 0; k0 < K; k0 += 64, ++it) {
        if (!DBUF) issue(k0, 0);
        __syncthreads();
        if (DBUF && k0 + 64 < K) issue(k0 + 64, (it + 1) & 1);
        const char* lp = (const char*)lds + (DBUF ? (it & 1) * (LDSZ * 2) : 0);
#pragma unroll
        for (int kk = 0; kk < 2; ++kk) {
            const int glq = kk * 4 + fq;
            const int sgl = (glq ^ sw) * 16;
            half8 aF[NI], bF[4];
#pragma unroll
            for (int i = 0; i < NI; ++i)
                aF[i] = *(const half8*)(lp + aOff[i] + sgl);
#pragma unroll
            for (int i = 0; i < 4; ++i)
                bF[i] = *(const half8*)(lp + bOff[i] + sgl);
#pragma unroll
            for (int mi = 0; mi < 4; ++mi)
#pragma unroll
                for (int ni = 0; ni < NI; ++ni)
                    acc[mi][ni] = __builtin_amdgcn_mfma_f32_16x16x32_f16(
                        aF[ni], bF[mi], acc[mi][ni], 0, 0, 0);
        }
        if (!DBUF) __syncthreads();
    }
    // ---- MODE 0, vt16 blocks (n0 >= 2048, block-uniform): LDS transpose ----
    if (MODE == 0 && n0 >= 2048) {
        __syncthreads();            // all K-loop LDS reads done; lds reusable
        f16* Tr = lds;              // [128 n_local][136] padded f16
#pragma unroll
        for (int mi = 0; mi < 4; ++mi) {
            const int ml = mi2 * 64 + mi * 16 + fr;
#pragma unroll
            for (int ni = 0; ni < NI; ++ni) {
                const int nl = ni2 * (NT / 2) + ni * 16 + 4 * fq;
                f32x4 a = acc[mi][ni];
#pragma unroll
                for (int r = 0; r < 4; ++r)
                    Tr[(nl + r) * 136 + ml] = (f16)a[r];
            }
        }
        __syncthreads();
        const int b = m0 >> 10, t0m = m0 & 1023;
        const int hh = (n0 >> 6) & 15;       // head for n_local 0..63
        const int row = tid >> 1, cb = (tid & 1) * 64;
        const size_t bh = (size_t)(b * 16 + hh + (row >> 6));
        const int d = row & 63;
        f16* dst = oVt + bh * 65536 + (size_t)d * 1024 + t0m + cb;
#pragma unroll
        for (int c = 0; c < 8; ++c)
            *(half8*)&dst[c * 8] = *(const half8*)&Tr[row * 136 + cb + c * 8];
        return;
    }
#pragma unroll
    for (int mi = 0; mi < 4; ++mi) {
        const int m = m0 + mi2 * 64 + mi * 16 + fr;
#pragma unroll
        for (int ni = 0; ni < NI; ++ni) {
            const int n = n0 + ni2 * (NT / 2) + ni * 16 + 4 * fq;
            if (MODE == 1) {
                *(f32x4*)(C + (size_t)m * 1024 + n) = acc[mi][ni];
            } else {
                const int w = n >> 10, h = (n >> 6) & 15, d = n & 63;
                const int b = m >> 10, t = m & 1023;
                const size_t bh = (size_t)(b * 16 + h);
                f32x4 a = acc[mi][ni];
                if (w == 0) {
                    half4v hv = {(f16)(a[0] * 0.125f), (f16)(a[1] * 0.125f),
                                 (f16)(a[2] * 0.125f), (f16)(a[3] * 0.125f)};
                    *(half4v*)&oQ[bh * 65536 + (size_t)t * 64 + d] = hv;
                } else {
                    half4v hv = {(f16)a[0], (f16)a[1], (f16)a[2], (f16)a[3]};
                    *(half4v*)&oK[bh * 65536 + (size_t)t * 64 + d] = hv;
                }
            }
        }
    }
}

// ---------------------------------------------------------------------------
// MFMA flash attention v3 (proven 52.4 us): 32x32x16 MFMAs, block = (bh,
// 128-row q-tile), 4 waves x 32 t. NO-max softmax. P in regs (shfl_xor(32)
// exchange). K/V staged unpadded+XOR-swizzled via global_load_lds into DOUBLE
// buffers: one barrier per iter; loads for tile j+1 fly during compute of j.
// ---------------------------------------------------------------------------
__global__ __launch_bounds__(256, 2) void attn_kernel(
    const f16* __restrict__ q16a, const f16* __restrict__ k16,
    const f16* __restrict__ vt16, const float* __restrict__ embQ,
    const float* __restrict__ embS, f16* __restrict__ heads16) {
    const int bh = blockIdx.x;
    const int t0 = blockIdx.y * 128;
    const f16* qg = q16a + (size_t)bh * 65536;
    const f16* kg = k16 + (size_t)bh * 65536;
    const f16* vg = vt16 + (size_t)bh * 65536;

    __shared__ f16 Kt[2][4096];     // [s][d] 64x64, swizzled; Kt[0] = eSt at end
    __shared__ f16 Vt[2][4096];     // [d][s] 64x64, swizzled
    __shared__ f16 qEl[66 * 136];   // [r][tl] r=0..64, tl=0..127
    __shared__ f16 band[128 * 72];  // [tl][k] raw scores; also embQ staging
                                    // (prologue) and O transpose (epilogue)
    __shared__ float e64s[64];

    const int tid = threadIdx.x;
    const int wv = tid >> 6, lane = tid & 63;
    const int tl32 = lane & 31, h = lane >> 5;
    const int tl = wv * 32 + tl32;       // 0..127
    const int tg = t0 + tl;

    auto stageKV = [&](int j0, int buf) {
#pragma unroll
        for (int i = 0; i < 2; ++i) {
            const int rt = wv * 16 + i * 8 + (lane >> 3);
            const int g = (lane & 7) ^ (rt & 7);
            __builtin_amdgcn_global_load_lds(
                (const __attribute__((address_space(1))) unsigned int*)
                    (kg + (size_t)(j0 + rt) * 64 + g * 8),
                (__attribute__((address_space(3))) unsigned int*)
                    &Kt[buf][(wv * 16 + i * 8) * 64], 16, 0, 0);
            __builtin_amdgcn_global_load_lds(
                (const __attribute__((address_space(1))) unsigned int*)
                    (vg + (size_t)rt * 1024 + j0 + g * 8),
                (__attribute__((address_space(3))) unsigned int*)
                    &Vt[buf][(wv * 16 + i * 8) * 64], 16, 0, 0);
        }
    };

    // Q B-frags first (oldest vmcnt slots), then preload tile 0 -> buffer 0.
    half8 qf[4];
#pragma unroll
    for (int ks = 0; ks < 4; ++ks)
        qf[ks] = *(const half8*)&qg[(size_t)tg * 64 + (2 * ks + h) * 8];
    stageKV(0, 0);

    // ---- stage embQ swizzled [row][64] into band space (rows 65..95 zero) --
    f16* embQs = band;
    for (int idx = tid; idx < 768; idx += 256) {
        const int row = idx >> 3, p = idx & 7, g = p ^ (row & 7);
        half8 hv;
        if (row < 65) {
            const float* s = embQ + row * 64 + g * 8;
#pragma unroll
            for (int j = 0; j < 8; ++j) hv[j] = (f16)s[j];
        } else {
#pragma unroll
            for (int j = 0; j < 8; ++j) hv[j] = (f16)0.f;
        }
        *(half8*)&embQs[row * 64 + p * 8] = hv;
    }
    __syncthreads();
    // ---- fused qE: qEl[r][tl] = embQ[r] . Q[tg]  (D: row=r, col=t) ----
    {
        f32x16 qacc[3];
#pragma unroll
        for (int mt = 0; mt < 3; ++mt)
#pragma unroll
            for (int r = 0; r < 16; ++r) qacc[mt][r] = 0.f;
#pragma unroll
        for (int ks = 0; ks < 4; ++ks)
#pragma unroll
            for (int mt = 0; mt < 3; ++mt) {
                const int row = tl32 + 32 * mt;
                const int p = (2 * ks + h) ^ (row & 7);
                half8 ef = *(const half8*)&embQs[row * 64 + p * 8];
                qacc[mt] = __builtin_amdgcn_mfma_f32_32x32x16_f16(
                    ef, qf[ks], qacc[mt], 0, 0, 0);
            }
        __syncthreads();   // embQs reads done; band space reusable
#pragma unroll
        for (int mt = 0; mt < 3; ++mt)
#pragma unroll
            for (int r = 0; r < 16; ++r) {
                const int rr = (r & 3) + 8 * (r >> 2) + 4 * h + 32 * mt;
                if (rr < 65) qEl[rr * 136 + tl] = (f16)qacc[mt][r];
            }
    }
    // init band to -1e4 (exp -> 0)
    for (int idx = tid; idx < 1152; idx += 256) {
        half8 hv;
#pragma unroll
        for (int j = 0; j < 8; ++j) hv[j] = (f16)(-1.0e4f);
        *(half8*)&band[idx * 8] = hv;
    }
    if (tid < 64) e64s[tid] = embS[64 * 64 + tid];
    __syncthreads();
    const float qE0 = (float)qEl[tl];
    const float qE64 = (float)qEl[64 * 136 + tl];

    float rs = 0.f, rsL = 0.f;
    f32x16 oacc[2];
#pragma unroll
    for (int dt = 0; dt < 2; ++dt)
#pragma unroll
        for (int r = 0; r < 16; ++r) oacc[dt][r] = 0.f;

    for (int jt = 0; jt < 16; ++jt) {
        const int j0 = jt * 64;
        __syncthreads();   // tile jt staged; prev compute's LDS reads done
        if (jt < 15) stageKV(j0 + 64, (jt + 1) & 1);
        const f16* Ktc = Kt[jt & 1];
        const f16* Vtc = Vt[jt & 1];
        // S^T = K @ Q^T : D[m=s][n=t], col = t(lane&31)
        f32x16 sacc[2];
#pragma unroll
        for (int mt = 0; mt < 2; ++mt)
#pragma unroll
            for (int r = 0; r < 16; ++r) sacc[mt][r] = 0.f;
#pragma unroll
        for (int ks = 0; ks < 4; ++ks)
#pragma unroll
            for (int mt = 0; mt < 2; ++mt) {
                const int row = tl32 + 32 * mt;
                const int p = (2 * ks + h) ^ (row & 7);
                half8 kf = *(const half8*)&Ktc[row * 64 + p * 8];
                sacc[mt] = __builtin_amdgcn_mfma_f32_32x32x16_f16(
                    kf, qf[ks], sacc[mt], 0, 0, 0);
            }
        // bias + exp (+band capture on diagonal tiles)
        const int dj = j0 - t0;
        if (dj <= -128 || dj >= 192) {
            const float bias = (dj < 0) ? qE0 : qE64;
            float ts = 0.f;
#pragma unroll
            for (int mt = 0; mt < 2; ++mt)
#pragma unroll
                for (int r = 0; r < 16; ++r) {
                    float pe = __expf(sacc[mt][r] + bias);
                    sacc[mt][r] = pe; ts += pe;
                }
            rs += ts;
            if (dj < 0) rsL += ts;
        } else {
#pragma unroll
            for (int mt = 0; mt < 2; ++mt)
#pragma unroll
                for (int r = 0; r < 16; ++r) {
                    const int sg = j0 + 32 * mt + (r & 3) + 8 * (r >> 2) + 4 * h;
                    const int ds = sg - tg;
                    const int dc = ds < -32 ? -32 : (ds > 32 ? 32 : ds);
                    float v = sacc[mt][r] + (float)qEl[(dc + 32) * 136 + tl];
                    if (ds >= -31 && ds <= 31) band[tl * 72 + ds + 31] = (f16)v;
                    float pe = __expf(v);
                    sacc[mt][r] = pe; rs += pe;
                    if (ds <= -32) rsL += pe;
                }
        }
        // PV: O[d][t] += V^T @ P^T ; P B-frag via half-wave shfl exchange
#pragma unroll
        for (int ks = 0; ks < 4; ++ks) {
            const int mtile = ks >> 1, rb = (ks & 1) * 8;
            float ex[4];
#pragma unroll
            for (int c = 0; c < 4; ++c) {
                float send = (h == 0) ? sacc[mtile][rb + 4 + c]
                                      : sacc[mtile][rb + c];
                ex[c] = __shfl_xor(send, 32);
            }
            half8 pf;
#pragma unroll
            for (int j = 0; j < 4; ++j)
                pf[j] = (f16)((h == 0) ? sacc[mtile][rb + j] : ex[j]);
#pragma unroll
            for (int j = 0; j < 4; ++j)
                pf[4 + j] = (f16)((h == 0) ? ex[j] : sacc[mtile][rb + 4 + j]);
#pragma unroll
            for (int dt = 0; dt < 2; ++dt) {
                const int row = tl32 + 32 * dt;
                const int p = (2 * ks + h) ^ (row & 7);
                half8 vf = *(const half8*)&Vtc[row * 64 + p * 8];
                // A = vf (rows = d), B = pf (cols = t)  ->  D[row=d][col=t]
                oacc[dt] = __builtin_amdgcn_mfma_f32_32x32x16_f16(
                    vf, pf, oacc[dt], 0, 0, 0);
            }
        }
    }
    // ---- epilogue ----
    rs += __shfl_xor(rs, 32);
    rsL += __shfl_xor(rsL, 32);
    // exp band in place; slot 63 = rsL (pairs embS[0] = left bucket)
    float sumBand = 0.f;
#pragma unroll
    for (int c = 0; c < 4; ++c) {
        const int kb = 32 * h + 8 * c;
        half8 bv = *(const half8*)&band[tl * 72 + kb];
        half8 ev;
#pragma unroll
        for (int j = 0; j < 8; ++j) {
            const int k = kb + j;
            float v;
            if (k == 63) v = rsL;
            else { v = __expf((float)bv[j]); sumBand += v; }
            ev[j] = (f16)v;
        }
        *(half8*)&band[tl * 72 + kb] = ev;
    }
    sumBand += __shfl_xor(sumBand, 32);
    const float sumR = rs - rsL - sumBand;
    // stage eSt[d][k] = embS[(k==63?0:k+1)][d] swizzled into Kt[0]
    // (last compute tile used buffers [1]; Kt[0] is free without a barrier)
    for (int idx = tid; idx < 512; idx += 256) {
        const int d = idx >> 3, p = idx & 7, g = p ^ (d & 7);
        half8 hv;
#pragma unroll
        for (int j = 0; j < 8; ++j) {
            const int k = g * 8 + j;
            hv[j] = (f16)embS[((k == 63) ? 0 : (k + 1)) * 64 + d];
        }
        *(half8*)&Kt[0][d * 64 + p * 8] = hv;
    }
    __syncthreads();
    // O += eSt @ Pband^T   (A = ef rows = d, B = pf cols = t)
#pragma unroll
    for (int ks = 0; ks < 4; ++ks) {
        half8 pf = *(const half8*)&band[tl * 72 + 16 * ks + 8 * h];
#pragma unroll
        for (int dt = 0; dt < 2; ++dt) {
            const int row = tl32 + 32 * dt;
            const int p = (2 * ks + h) ^ (row & 7);
            half8 ef = *(const half8*)&Kt[0][row * 64 + p * 8];
            oacc[dt] = __builtin_amdgcn_mfma_f32_32x32x16_f16(
                ef, pf, oacc[dt], 0, 0, 0);
        }
    }
    __syncthreads();   // band (Pband) reads done before O-transpose overwrite
    // O (row=d, col=own t) -> band space [tl][d], then coalesced global store
    const float inv = 1.0f / rs;
#pragma unroll
    for (int dt = 0; dt < 2; ++dt)
#pragma unroll
        for (int r = 0; r < 16; ++r) {
            const int d = (r & 3) + 8 * (r >> 2) + 4 * h + 32 * dt;
            band[tl * 72 + d] = (f16)((oacc[dt][r] + sumR * e64s[d]) * inv);
        }
    __syncthreads();
    const int b = bh >> 4, hh = bh & 15;
    const int row = tid >> 1, cb = (tid & 1) * 32;
    f16* dst = heads16 + ((size_t)(b * 1024 + t0 + row) * 1024) + hh * 64 + cb;
#pragma unroll
    for (int c = 0; c < 4; ++c)
        *(half8*)&dst[c * 8] = *(const half8*)&band[row * 72 + cb + c * 8];
}

// ---------------------------------------------------------------------------
extern "C" void kernel_launch(void* const* d_in, const int* in_sizes, int n_in,
                              void* d_out, int out_size, void* d_ws, size_t ws_size,
                              hipStream_t stream) {
    const float* query = (const float*)d_in[0];
    const float* value = (const float*)d_in[1];
    const float* WQ   = (const float*)d_in[2];
    const float* WK   = (const float*)d_in[3];
    const float* WV   = (const float*)d_in[4];
    const float* WO   = (const float*)d_in[5];
    const float* embQ = (const float*)d_in[6];
    const float* embS = (const float*)d_in[7];
    float* out = (float*)d_out;

    f16* w0    = (f16*)d_ws;
    f16* q16   = w0;                 // 4,194,304 h (+ v16 contiguous)
    f16* v16   = w0 + 4194304;       // 4,194,304 h
    f16* Wt16  = w0 + 8388608;       // 3,145,728 h
    f16* WOt16 = w0 + 11534336;      // 1,048,576 h
    f16* q16a  = w0 + 12582912;      // 4,194,304 h (qW/8)
    f16* k16   = w0 + 16777216;      // 4,194,304 h
    f16* vt16  = w0 + 20971520;      // 4,194,304 h (V transposed [bh][d][t])
    f16* h16   = w0 + 25165824;      // 4,194,304 h  (end: 58.7 MB)

    prep<<<9216, 256, 0, stream>>>(query, value, WQ, WK, WV, WO,
                                   q16, Wt16, WOt16);
    mfma_gemm<0, 128, true><<<768, 256, 0, stream>>>(
        q16, v16, Wt16, nullptr, q16a, k16, vt16);
    attn_kernel<<<dim3(64, 8), 256, 0, stream>>>(q16a, k16, vt16, embQ, embS, h16);
    mfma_gemm<1, 64, true><<<512, 256, 0, stream>>>(
        h16, h16, WOt16, out, nullptr, nullptr, nullptr);
}